// Round 2
// baseline (3067.954 us; speedup 1.0000x reference)
//
#include <hip/hip_runtime.h>
#include <math.h>

// MLLA block, f32 implementation, adaptive workspace (round 2).
// B=16, L=2304 (48x48), D=384, 12 heads x 32, MLP=1536.
// Per-batch-group pipeline: 4 group-units of ws + d_out slice as 5th buffer.

#define L_TOK 2304
#define DIM   384
#define NHEADS 12
#define BATCH 16
#define HIMG  48
#define WIMG  48
#define UNITB ((size_t)L_TOK * DIM)    // 884,736 floats per batch

enum { M_BIAS = 0, M_SILU = 1, M_ELU1 = 2, M_GELU = 3, M_RES = 4, M_ACC = 5 };

__device__ __forceinline__ float siluf(float x) { return x / (1.0f + expf(-x)); }
__device__ __forceinline__ float geluf(float x) { return 0.5f * x * (1.0f + erff(x * 0.70710678118654752f)); }

// ---------------- diagnostic sentinel ----------------
__global__ void sentinel_k(float* out, float v) { out[0] = v; }

// ---------------- RoPE tables: cos/sin[(h*48+w)*192 + p] ----------------
__global__ __launch_bounds__(256) void rope_tab_k(float* __restrict__ cosT, float* __restrict__ sinT) {
    int i = blockIdx.x * 256 + threadIdx.x;
    if (i >= L_TOK * 192) return;
    int n = i / 192, p = i % 192;
    int h = n / WIMG, w = n % WIMG;
    int j = (p < 96) ? p : p - 96;
    float pos = (p < 96) ? (float)h : (float)w;
    float theta = expf(-(float)j * (9.210340371976184f / 96.0f));  // 10000^(-j/96)
    float ang = pos * theta;
    cosT[i] = cosf(ang);
    sinT[i] = sinf(ang);
}

// ---------------- depthwise 3x3 SAME conv (group-local, nb batches) ----------------
// mode 0: out = src + conv(src);  mode 1: out = silu(conv(src));  mode 2: out += conv(src)
__global__ __launch_bounds__(256) void dwconv_k(const float* __restrict__ src,
                                                const float* __restrict__ wgt,
                                                const float* __restrict__ bias,
                                                float* __restrict__ out, int mode) {
    int idx = blockIdx.x * 256 + threadIdx.x;   // grid exactly covers nb*L_TOK*DIM
    int c = idx % DIM;
    int t = idx / DIM;
    int w = t % WIMG;
    int h = (t / WIMG) % HIMG;
    int b = t / (WIMG * HIMG);
    const float* wc = wgt + c * 9;
    float s = bias[c];
    const size_t base = (size_t)b * (L_TOK * DIM);
#pragma unroll
    for (int kh = 0; kh < 3; ++kh) {
        int hh = h + kh - 1;
        if ((unsigned)hh >= (unsigned)HIMG) continue;
#pragma unroll
        for (int kw = 0; kw < 3; ++kw) {
            int ww = w + kw - 1;
            if ((unsigned)ww >= (unsigned)WIMG) continue;
            s = fmaf(src[base + (size_t)(hh * WIMG + ww) * DIM + c], wc[kh * 3 + kw], s);
        }
    }
    if (mode == 0)      out[idx] = src[idx] + s;
    else if (mode == 1) out[idx] = siluf(s);
    else                out[idx] += s;
}

// ---------------- LayerNorm over last dim (384), one wave per row ----------------
__global__ __launch_bounds__(256) void ln_k(const float* __restrict__ in,
                                            const float* __restrict__ w,
                                            const float* __restrict__ b,
                                            float* __restrict__ out) {
    const int row = blockIdx.x * 4 + (threadIdx.x >> 6);
    const int lane = threadIdx.x & 63;
    const float* x = in + (size_t)row * DIM;
    float v[6];
    float s = 0.f;
#pragma unroll
    for (int i = 0; i < 6; ++i) { v[i] = x[lane + i * 64]; s += v[i]; }
#pragma unroll
    for (int o = 32; o > 0; o >>= 1) s += __shfl_xor(s, o, 64);
    const float mean = s * (1.0f / DIM);
    float q = 0.f;
#pragma unroll
    for (int i = 0; i < 6; ++i) { float d = v[i] - mean; q = fmaf(d, d, q); }
#pragma unroll
    for (int o = 32; o > 0; o >>= 1) q += __shfl_xor(q, o, 64);
    const float rs = 1.0f / sqrtf(q * (1.0f / DIM) + 1e-5f);
    float* o2 = out + (size_t)row * DIM;
#pragma unroll
    for (int i = 0; i < 6; ++i) {
        int d = lane + i * 64;
        o2[d] = fmaf((v[i] - mean) * rs, w[d], b[d]);
    }
}

// ---------------- GEMM: C[M,N] = A[M,K] @ W[N,K]^T (+epilogue) ----------------
// 128x128 tile, BK=8, 256 threads, 8x8 micro-tile. K mult of 8; M,N mult of 128.
__global__ __launch_bounds__(256) void gemm_nt(const float* __restrict__ A, int lda,
                                               const float* __restrict__ W, int ldw,
                                               const float* __restrict__ bias,
                                               const float* __restrict__ res,
                                               float* __restrict__ Cout, int ldc,
                                               int K, int mode) {
    __shared__ float As[8][132];
    __shared__ float Ws[8][132];
    const int tid = threadIdx.x;
    const int m0 = blockIdx.y * 128;
    const int n0 = blockIdx.x * 128;
    const int lr = tid >> 1;             // 0..127 (tile row)
    const int lk = (tid & 1) * 4;        // 0 or 4 (k sub-offset)
    const float* Ap = A + (size_t)(m0 + lr) * lda + lk;
    const float* Wp = W + (size_t)(n0 + lr) * ldw + lk;
    const int tx = tid & 15, ty = tid >> 4;
    const int rm = ty * 8, rn = tx * 8;
    float acc[8][8];
#pragma unroll
    for (int i = 0; i < 8; ++i)
#pragma unroll
        for (int j = 0; j < 8; ++j) acc[i][j] = 0.f;

    for (int k0 = 0; k0 < K; k0 += 8) {
        float4 av = *(const float4*)(Ap + k0);
        float4 wv = *(const float4*)(Wp + k0);
        __syncthreads();
        As[lk + 0][lr] = av.x; As[lk + 1][lr] = av.y; As[lk + 2][lr] = av.z; As[lk + 3][lr] = av.w;
        Ws[lk + 0][lr] = wv.x; Ws[lk + 1][lr] = wv.y; Ws[lk + 2][lr] = wv.z; Ws[lk + 3][lr] = wv.w;
        __syncthreads();
#pragma unroll
        for (int kk = 0; kk < 8; ++kk) {
            float4 a0 = *(const float4*)&As[kk][rm];
            float4 a1 = *(const float4*)&As[kk][rm + 4];
            float4 b0 = *(const float4*)&Ws[kk][rn];
            float4 b1 = *(const float4*)&Ws[kk][rn + 4];
            float a[8] = {a0.x, a0.y, a0.z, a0.w, a1.x, a1.y, a1.z, a1.w};
            float b[8] = {b0.x, b0.y, b0.z, b0.w, b1.x, b1.y, b1.z, b1.w};
#pragma unroll
            for (int i = 0; i < 8; ++i)
#pragma unroll
                for (int j = 0; j < 8; ++j) acc[i][j] = fmaf(a[i], b[j], acc[i][j]);
        }
    }
#pragma unroll
    for (int i = 0; i < 8; ++i) {
        const int m = m0 + rm + i;
#pragma unroll
        for (int j = 0; j < 8; ++j) {
            const int n = n0 + rn + j;
            float v = acc[i][j];
            if (mode != M_ACC && bias != nullptr) v += bias[n];
            if (mode == M_SILU)      v = siluf(v);
            else if (mode == M_ELU1) v = (v > 0.f) ? (v + 1.f) : expf(v);
            else if (mode == M_GELU) v = geluf(v);
            const size_t oi = (size_t)m * ldc + n;
            if (mode == M_RES)      v += res[oi];
            else if (mode == M_ACC) v += Cout[oi];
            Cout[oi] = v;
        }
    }
}

// ---------------- kmean: column mean of k (M x 384 layout), two-stage ----------------
__global__ __launch_bounds__(384) void kmean_part_k(const float* __restrict__ kbuf, float* __restrict__ part, int nb) {
    const int b = blockIdx.x, chunk = blockIdx.y;   // nb x 9
    const int c = threadIdx.x;
    const float* p = kbuf + ((size_t)(b * L_TOK + chunk * 256)) * DIM + c;
    float s = 0.f;
    for (int n = 0; n < 256; ++n) s += p[(size_t)n * DIM];
    part[(size_t)(chunk * nb + b) * DIM + c] = s;
}

__global__ __launch_bounds__(384) void kmean_fin_k(const float* __restrict__ part, float* __restrict__ km, int nb) {
    const int b = blockIdx.x, c = threadIdx.x;
    float s = 0.f;
#pragma unroll
    for (int ch = 0; ch < 9; ++ch) s += part[(size_t)(ch * nb + b) * DIM + c];
    km[b * DIM + c] = s * (1.0f / L_TOK);
}

// ---------------- kv[b,h,d,e] = (1/L) sum_n rope(k)[n,d] * v[n,e] ----------------
__global__ __launch_bounds__(256) void kv_k(const float* __restrict__ kbuf, const float* __restrict__ xi,
                                            const float* __restrict__ cosT, const float* __restrict__ sinT,
                                            float* __restrict__ kv) {
    const int b = blockIdx.x / NHEADS, h = blockIdx.x % NHEADS;
    __shared__ float ks[64][33];
    __shared__ float vs[64][33];
    const int tid = threadIdx.x;
    const int e0 = (tid & 15) * 2;
    const int d0 = (tid >> 4) * 2;
    float acc00 = 0.f, acc01 = 0.f, acc10 = 0.f, acc11 = 0.f;
    for (int n0 = 0; n0 < L_TOK; n0 += 64) {
#pragma unroll
        for (int j = 0; j < 4; ++j) {           // 1024 rope pairs
            int pi = tid + j * 256;
            int tn = pi >> 4;
            int pd = pi & 15;
            int n = n0 + tn;
            const float* kp = kbuf + ((size_t)(b * L_TOK + n)) * DIM + h * 32 + pd * 2;
            float ka = kp[0], kb = kp[1];
            float cs = cosT[n * 192 + h * 16 + pd];
            float sn = sinT[n * 192 + h * 16 + pd];
            ks[tn][pd * 2]     = cs * ka - sn * kb;
            ks[tn][pd * 2 + 1] = sn * ka + cs * kb;
        }
#pragma unroll
        for (int j = 0; j < 8; ++j) {           // 2048 v elems
            int vi = tid + j * 256;
            int tn = vi >> 5;
            int d = vi & 31;
            vs[tn][d] = xi[((size_t)(b * L_TOK + n0 + tn)) * DIM + h * 32 + d];
        }
        __syncthreads();
#pragma unroll 8
        for (int n = 0; n < 64; ++n) {
            float k0v = ks[n][d0], k1v = ks[n][d0 + 1];
            float v0 = vs[n][e0], v1 = vs[n][e0 + 1];
            acc00 = fmaf(k0v, v0, acc00);
            acc01 = fmaf(k0v, v1, acc01);
            acc10 = fmaf(k1v, v0, acc10);
            acc11 = fmaf(k1v, v1, acc11);
        }
        __syncthreads();
    }
    const float inv = 1.0f / (float)L_TOK;
    float* o = kv + ((size_t)blockIdx.x * 32 + d0) * 32 + e0;
    o[0] = acc00 * inv; o[1] = acc01 * inv;
    o[32] = acc10 * inv; o[33] = acc11 * inv;
}

// ---------------- att[b,n,c] = z(b,h,n) * sum_d rope(q)[n,h,d] * kv[b,h,d,e] ----------------
__global__ __launch_bounds__(384) void att_k(const float* __restrict__ q, const float* __restrict__ kv,
                                             const float* __restrict__ km,
                                             const float* __restrict__ cosT, const float* __restrict__ sinT,
                                             float* __restrict__ out) {
    __shared__ float kvs[NHEADS * 32 * 32];   // 48 KB
    __shared__ float kms[DIM];
    __shared__ float sq[DIM];
    __shared__ float sqr[DIM];
    const int b = blockIdx.x / 48;
    const int chunk = blockIdx.x % 48;
    const int tid = threadIdx.x;
    for (int i = tid; i < NHEADS * 1024; i += 384) kvs[i] = kv[(size_t)b * (NHEADS * 1024) + i];
    kms[tid] = km[b * DIM + tid];
    __syncthreads();
    const int h = tid >> 5, e = tid & 31;
    const int p = tid >> 1;
    const float* kvh = &kvs[h * 1024];
    for (int ni = 0; ni < 48; ++ni) {
        const int n = chunk * 48 + ni;
        const float qv = q[((size_t)(b * L_TOK + n)) * DIM + tid];
        sq[tid] = qv;
        __syncthreads();
        float a = sq[tid & ~1], bb = sq[tid | 1];
        float cs = cosT[n * 192 + p], sn = sinT[n * 192 + p];
        sqr[tid] = (tid & 1) ? fmaf(sn, a, cs * bb) : fmaf(cs, a, -sn * bb);
        float zp = qv * kms[tid];
#pragma unroll
        for (int o = 16; o > 0; o >>= 1) zp += __shfl_xor(zp, o, 32);
        const float z = 1.0f / (zp + 1e-6f);
        __syncthreads();
        float dot = 0.f;
        const float* qrh = &sqr[h * 32];
#pragma unroll 8
        for (int d = 0; d < 32; ++d) dot = fmaf(qrh[d], kvh[d * 32 + e], dot);
        out[((size_t)(b * L_TOK + n)) * DIM + tid] = z * dot;
        __syncthreads();
    }
}

// ---------------- elementwise multiply (float4) ----------------
__global__ __launch_bounds__(256) void mul_k(const float* __restrict__ a, const float* __restrict__ b,
                                             float* __restrict__ o) {
    int i = blockIdx.x * 256 + threadIdx.x;     // grid covers nb*UNITB/4 exactly
    float4 x = ((const float4*)a)[i];
    float4 y = ((const float4*)b)[i];
    float4 r;
    r.x = x.x * y.x; r.y = x.y * y.y; r.z = x.z * y.z; r.w = x.w * y.w;
    ((float4*)o)[i] = r;
}

extern "C" void kernel_launch(void* const* d_in, const int* in_sizes, int n_in,
                              void* d_out, int out_size, void* d_ws, size_t ws_size,
                              hipStream_t stream) {
    const float* x       = (const float*)d_in[0];
    const float* cpe1_w  = (const float*)d_in[3];
    const float* cpe1_b  = (const float*)d_in[4];
    const float* norm1_w = (const float*)d_in[5];
    const float* norm1_b = (const float*)d_in[6];
    const float* in_w    = (const float*)d_in[7];
    const float* in_b    = (const float*)d_in[8];
    const float* act_w   = (const float*)d_in[9];
    const float* act_b   = (const float*)d_in[10];
    const float* dwc_w   = (const float*)d_in[11];
    const float* dwc_b   = (const float*)d_in[12];
    const float* qk_w    = (const float*)d_in[13];
    const float* qk_b    = (const float*)d_in[14];
    const float* lepe_w  = (const float*)d_in[15];
    const float* lepe_b  = (const float*)d_in[16];
    const float* outp_w  = (const float*)d_in[17];
    const float* outp_b  = (const float*)d_in[18];
    const float* cpe2_w  = (const float*)d_in[19];
    const float* cpe2_b  = (const float*)d_in[20];
    const float* norm2_w = (const float*)d_in[21];
    const float* norm2_b = (const float*)d_in[22];
    const float* fc1_w   = (const float*)d_in[23];
    const float* fc1_b   = (const float*)d_in[24];
    const float* fc2_w   = (const float*)d_in[25];
    const float* fc2_b   = (const float*)d_in[26];
    float* out = (float*)d_out;

    float* ws = (float*)d_ws;
    const size_t TAB = (size_t)L_TOK * 192;                      // 442368 floats per table
    // fixed small region (sized for max nb=16): cos, sin, km, part, kv
    const size_t SMALL = 2 * TAB + (size_t)BATCH * DIM + 9 * (size_t)BATCH * DIM
                       + (size_t)BATCH * NHEADS * 1024;          // ~1.14 M floats
    float* cosT = ws;
    float* sinT = cosT + TAB;
    float* km   = sinT + TAB;
    float* part = km + (size_t)BATCH * DIM;
    float* kvb  = part + 9 * (size_t)BATCH * DIM;
    float* gbuf = ws + SMALL;                                    // 4 group-units follow

    // pick largest batch-group size whose 4 units fit in the remaining ws
    const size_t avail = (ws_size / 4 > SMALL) ? (ws_size / 4 - SMALL) : 0;
    int nb = 0;
    for (int cand = BATCH; cand >= 1; cand >>= 1)
        if (4 * (size_t)cand * UNITB <= avail) { nb = cand; break; }
    if (nb == 0) {   // diagnosable: out[0] = ws_size in MB
        sentinel_k<<<1, 1, 0, stream>>>(out, (float)(ws_size >> 20));
        return;
    }

    rope_tab_k<<<(int)((TAB + 255) / 256), 256, 0, stream>>>(cosT, sinT);

    for (int b0 = 0; b0 < BATCH; b0 += nb) {
        const size_t goff = (size_t)b0 * UNITB;
        const size_t GU   = (size_t)nb * UNITB;
        float* W0 = gbuf;             // x1 / x3
        float* W1 = gbuf + GU;        // xn / q / ao / xn2
        float* W2 = gbuf + 2 * GU;    // xi0 / act_res / x2 / h-chunk
        float* W3 = gbuf + 3 * GU;    // xi
        float* O  = out + goff;       // k / att / final out
        const float* Xg = x + goff;

        const int EW_GRID = (int)(GU / 256);
        const dim3 G384(3, nb * 18);

        // x1 = x + dwconv(x, cpe1)
        dwconv_k<<<EW_GRID, 256, 0, stream>>>(Xg, cpe1_w, cpe1_b, W0, 0);
        // xn = LN(x1)
        ln_k<<<nb * 576, 256, 0, stream>>>(W0, norm1_w, norm1_b, W1);
        // xi0 = xn @ in_proj^T + b
        gemm_nt<<<G384, 256, 0, stream>>>(W1, DIM, in_w, DIM, in_b, nullptr, W2, DIM, DIM, M_BIAS);
        // xi = silu(dwconv(xi0, dwc))
        dwconv_k<<<EW_GRID, 256, 0, stream>>>(W2, dwc_w, dwc_b, W3, 1);
        // act_res = silu(xn @ act_proj^T + b)
        gemm_nt<<<G384, 256, 0, stream>>>(W1, DIM, act_w, DIM, act_b, nullptr, W2, DIM, DIM, M_SILU);
        // q = elu(xi @ qk_w[:384]^T + b[:384]) + 1   -> W1 (overwrites xn)
        gemm_nt<<<G384, 256, 0, stream>>>(W3, DIM, qk_w, DIM, qk_b, nullptr, W1, DIM, DIM, M_ELU1);
        // k = elu(xi @ qk_w[384:]^T + b[384:]) + 1   -> O
        gemm_nt<<<G384, 256, 0, stream>>>(W3, DIM, qk_w + (size_t)DIM * DIM, DIM, qk_b + DIM,
                                          nullptr, O, DIM, DIM, M_ELU1);
        // kmean over k
        kmean_part_k<<<dim3(nb, 9), 384, 0, stream>>>(O, part, nb);
        kmean_fin_k<<<nb, 384, 0, stream>>>(part, km, nb);
        // kv state from rope(k), v=xi
        kv_k<<<nb * NHEADS, 256, 0, stream>>>(O, W3, cosT, sinT, kvb);
        // att -> O (overwrites k)
        att_k<<<nb * 48, 384, 0, stream>>>(W1, kvb, km, cosT, sinT, O);
        // att += dwconv(xi, lepe)
        dwconv_k<<<EW_GRID, 256, 0, stream>>>(W3, lepe_w, lepe_b, O, 2);
        // ao = att * act_res -> W1 (overwrites q)
        mul_k<<<(int)(GU / 4 / 256), 256, 0, stream>>>(O, W2, W1);
        // x2 = x1 + ao @ out_proj^T + b -> W2
        gemm_nt<<<G384, 256, 0, stream>>>(W1, DIM, outp_w, DIM, outp_b, W0, W2, DIM, DIM, M_RES);
        // x3 = x2 + dwconv(x2, cpe2) -> W0
        dwconv_k<<<EW_GRID, 256, 0, stream>>>(W2, cpe2_w, cpe2_b, W0, 0);
        // xn2 = LN(x3) -> W1
        ln_k<<<nb * 576, 256, 0, stream>>>(W0, norm2_w, norm2_b, W1);
        // MLP in 4 chunks of 384: O = x3 + gelu(xn2@fc1^T)@fc2^T + b2
        for (int c = 0; c < 4; ++c) {
            gemm_nt<<<G384, 256, 0, stream>>>(W1, DIM, fc1_w + (size_t)c * 384 * DIM, DIM,
                                              fc1_b + c * 384, nullptr, W2, DIM, DIM, M_GELU);
            gemm_nt<<<G384, 256, 0, stream>>>(W2, DIM, fc2_w + c * 384, 1536,
                                              (c == 0) ? fc2_b : nullptr,
                                              (c == 0) ? W0 : nullptr,
                                              O, DIM, DIM, (c == 0) ? M_RES : M_ACC);
        }
    }
}

// Round 3
// 1544.939 us; speedup vs baseline: 1.9858x; 1.9858x over previous
//
#include <hip/hip_runtime.h>
#include <math.h>

// MLLA block, round 3: bf16-MFMA GEMMs (m97-style global_load_lds staging),
// f32 everything else. B=16, L=2304 (48x48), D=384, 12 heads x 32, MLP=1536.

#define L_TOK 2304
#define DIM   384
#define NHEADS 12
#define BATCH 16
#define HIMG  48
#define WIMG  48
#define UNITB ((size_t)L_TOK * DIM)    // 884,736 floats per batch

typedef unsigned short u16;
typedef __attribute__((ext_vector_type(8))) short bf16x8;
typedef __attribute__((ext_vector_type(4))) float f32x4;

enum { M_BIAS = 0, M_SILU = 1, M_ELU1 = 2, M_GELU = 3, M_RES = 4, M_ACC = 5 };

__device__ __forceinline__ float siluf(float x) { return x / (1.0f + expf(-x)); }
__device__ __forceinline__ float geluf(float x) { return 0.5f * x * (1.0f + erff(x * 0.70710678118654752f)); }
__device__ __forceinline__ u16 f2bf(float f) {   // RNE f32->bf16
    unsigned u = __float_as_uint(f);
    u += 0x7fffu + ((u >> 16) & 1u);
    return (u16)(u >> 16);
}

__global__ void sentinel_k(float* out, float v) { out[0] = v; }

// ---------------- weight f32 -> bf16 (n multiple of 1024) ----------------
__global__ __launch_bounds__(256) void cvtw_k(const float* __restrict__ src, u16* __restrict__ dst) {
    int i = blockIdx.x * 256 + threadIdx.x;
    float4 v = ((const float4*)src)[i];
    ushort4 o;
    o.x = f2bf(v.x); o.y = f2bf(v.y); o.z = f2bf(v.z); o.w = f2bf(v.w);
    ((ushort4*)dst)[i] = o;
}

// ---------------- RoPE tables: cos/sin[(h*48+w)*192 + p] ----------------
__global__ __launch_bounds__(256) void rope_tab_k(float* __restrict__ cosT, float* __restrict__ sinT) {
    int i = blockIdx.x * 256 + threadIdx.x;
    if (i >= L_TOK * 192) return;
    int n = i / 192, p = i % 192;
    int h = n / WIMG, w = n % WIMG;
    int j = (p < 96) ? p : p - 96;
    float pos = (p < 96) ? (float)h : (float)w;
    float theta = expf(-(float)j * (9.210340371976184f / 96.0f));  // 10000^(-j/96)
    float ang = pos * theta;
    cosT[i] = cosf(ang);
    sinT[i] = sinf(ang);
}

// ---------------- depthwise 3x3 SAME conv ----------------
// mode 0: out = src + conv(src);  mode 1: out = silu(conv) (+bf16 copy);  mode 2: out += conv(src)
__global__ __launch_bounds__(256) void dwconv_k(const float* __restrict__ src,
                                                const float* __restrict__ wgt,
                                                const float* __restrict__ bias,
                                                float* __restrict__ out,
                                                u16* __restrict__ out_bf, int mode) {
    int idx = blockIdx.x * 256 + threadIdx.x;   // grid exactly covers nb*L_TOK*DIM
    int c = idx % DIM;
    int t = idx / DIM;
    int w = t % WIMG;
    int h = (t / WIMG) % HIMG;
    int b = t / (WIMG * HIMG);
    const float* wc = wgt + c * 9;
    float s = bias[c];
    const size_t base = (size_t)b * (L_TOK * DIM);
#pragma unroll
    for (int kh = 0; kh < 3; ++kh) {
        int hh = h + kh - 1;
        if ((unsigned)hh >= (unsigned)HIMG) continue;
#pragma unroll
        for (int kw = 0; kw < 3; ++kw) {
            int ww = w + kw - 1;
            if ((unsigned)ww >= (unsigned)WIMG) continue;
            s = fmaf(src[base + (size_t)(hh * WIMG + ww) * DIM + c], wc[kh * 3 + kw], s);
        }
    }
    if (mode == 0)      out[idx] = src[idx] + s;
    else if (mode == 1) { float r = siluf(s); out[idx] = r; out_bf[idx] = f2bf(r); }
    else                out[idx] += s;
}

// ---------------- LayerNorm over last dim (384) -> bf16, one wave per row ----------------
__global__ __launch_bounds__(256) void ln_k(const float* __restrict__ in,
                                            const float* __restrict__ w,
                                            const float* __restrict__ b,
                                            u16* __restrict__ out) {
    const int row = blockIdx.x * 4 + (threadIdx.x >> 6);
    const int lane = threadIdx.x & 63;
    const float* x = in + (size_t)row * DIM;
    float v[6];
    float s = 0.f;
#pragma unroll
    for (int i = 0; i < 6; ++i) { v[i] = x[lane + i * 64]; s += v[i]; }
#pragma unroll
    for (int o = 32; o > 0; o >>= 1) s += __shfl_xor(s, o, 64);
    const float mean = s * (1.0f / DIM);
    float q = 0.f;
#pragma unroll
    for (int i = 0; i < 6; ++i) { float d = v[i] - mean; q = fmaf(d, d, q); }
#pragma unroll
    for (int o = 32; o > 0; o >>= 1) q += __shfl_xor(q, o, 64);
    const float rs = 1.0f / sqrtf(q * (1.0f / DIM) + 1e-5f);
    u16* o2 = out + (size_t)row * DIM;
#pragma unroll
    for (int i = 0; i < 6; ++i) {
        int d = lane + i * 64;
        o2[d] = f2bf(fmaf((v[i] - mean) * rs, w[d], b[d]));
    }
}

// ---------------- bf16 MFMA GEMM: C[M,N] = A[M,K]bf16 @ Wt[N,K]bf16^T (+epilogue) ----------------
// 128x128 tile, BK=32, 256 threads (4 waves, each 64x64 = 4x4 16x16 fragments).
// A,Wt row-major bf16 with K contiguous. M mult of 128, N mult of 128, K mult of 32.
// LDS [128 rows][32 k] bf16 per operand, staged via global_load_lds width-16.
__global__ __launch_bounds__(256) void gemm_bf16(const u16* __restrict__ A, int lda,
                                                 const u16* __restrict__ Wt, int ldw,
                                                 const float* __restrict__ bias,
                                                 const float* __restrict__ res,
                                                 float* __restrict__ Cf, u16* __restrict__ Cb,
                                                 int ldc, int K, int mode) {
    __shared__ u16 As[128 * 32];
    __shared__ u16 Bs[128 * 32];
    const int tid = threadIdx.x;
    const int l = tid & 63;
    const int w = tid >> 6;
    const int m0 = blockIdx.y * 128, n0 = blockIdx.x * 128;
    const int fr = l & 15, kb = l >> 4;          // fragment row, k-block
    const int wm = (w >> 1) * 64, wn = (w & 1) * 64;
    f32x4 acc[4][4];
#pragma unroll
    for (int i = 0; i < 4; ++i)
#pragma unroll
        for (int j = 0; j < 4; ++j) acc[i][j] = (f32x4){0.f, 0.f, 0.f, 0.f};

    for (int k0 = 0; k0 < K; k0 += 32) {
        // stage: chunk = row*4 + slot (16B each); wave w handles chunks [w*64, w*64+64) and +256
#pragma unroll
        for (int i = 0; i < 2; ++i) {
            const int chb = i * 256 + w * 64;    // wave-uniform chunk base
            const int ch = chb + l;              // per-lane chunk
            const u16* ga = A + (size_t)(m0 + (ch >> 2)) * lda + (k0 + (ch & 3) * 8);
            __builtin_amdgcn_global_load_lds((const __attribute__((address_space(1))) void*)ga,
                                             (__attribute__((address_space(3))) void*)(As + chb * 8),
                                             16, 0, 0);
            const u16* gb = Wt + (size_t)(n0 + (ch >> 2)) * ldw + (k0 + (ch & 3) * 8);
            __builtin_amdgcn_global_load_lds((const __attribute__((address_space(1))) void*)gb,
                                             (__attribute__((address_space(3))) void*)(Bs + chb * 8),
                                             16, 0, 0);
        }
        asm volatile("s_waitcnt vmcnt(0)" ::: "memory");
        __syncthreads();
        bf16x8 af[4], bfr[4];
#pragma unroll
        for (int mi = 0; mi < 4; ++mi) af[mi] = *(const bf16x8*)&As[(wm + mi * 16 + fr) * 32 + kb * 8];
#pragma unroll
        for (int ni = 0; ni < 4; ++ni) bfr[ni] = *(const bf16x8*)&Bs[(wn + ni * 16 + fr) * 32 + kb * 8];
#pragma unroll
        for (int mi = 0; mi < 4; ++mi)
#pragma unroll
            for (int ni = 0; ni < 4; ++ni)
                acc[mi][ni] = __builtin_amdgcn_mfma_f32_16x16x32_bf16(af[mi], bfr[ni], acc[mi][ni], 0, 0, 0);
        __syncthreads();
    }
    // epilogue: C row = (lane>>4)*4 + reg (A side), col = lane&15 (W side)  [m89-verified]
    const int orow = (l >> 4) * 4, ocol = l & 15;
#pragma unroll
    for (int mi = 0; mi < 4; ++mi) {
#pragma unroll
        for (int ni = 0; ni < 4; ++ni) {
            const int n = n0 + wn + ni * 16 + ocol;
            const float bv = (mode != M_ACC) ? bias[n] : 0.f;
#pragma unroll
            for (int r = 0; r < 4; ++r) {
                const int m = m0 + wm + mi * 16 + orow + r;
                float v = acc[mi][ni][r] + bv;
                if (mode == M_SILU)      v = siluf(v);
                else if (mode == M_ELU1) v = (v > 0.f) ? (v + 1.f) : expf(v);
                else if (mode == M_GELU) v = geluf(v);
                const size_t oi = (size_t)m * ldc + n;
                if (mode == M_RES)      v += res[oi];
                else if (mode == M_ACC) v += Cf[oi];
                if (mode == M_GELU) Cb[oi] = f2bf(v);
                else                Cf[oi] = v;
            }
        }
    }
}

// ---------------- kmean: column mean of k (M x 384 layout), two-stage ----------------
__global__ __launch_bounds__(384) void kmean_part_k(const float* __restrict__ kbuf, float* __restrict__ part, int nb) {
    const int b = blockIdx.x, chunk = blockIdx.y;   // nb x 9
    const int c = threadIdx.x;
    const float* p = kbuf + ((size_t)(b * L_TOK + chunk * 256)) * DIM + c;
    float s = 0.f;
    for (int n = 0; n < 256; ++n) s += p[(size_t)n * DIM];
    part[(size_t)(chunk * nb + b) * DIM + c] = s;
}

__global__ __launch_bounds__(384) void kmean_fin_k(const float* __restrict__ part, float* __restrict__ km, int nb) {
    const int b = blockIdx.x, c = threadIdx.x;
    float s = 0.f;
#pragma unroll
    for (int ch = 0; ch < 9; ++ch) s += part[(size_t)(ch * nb + b) * DIM + c];
    km[b * DIM + c] = s * (1.0f / L_TOK);
}

// ---------------- kv[b,h,d,e] = (1/L) sum_n rope(k)[n,d] * v[n,e] ----------------
__global__ __launch_bounds__(256) void kv_k(const float* __restrict__ kbuf, const float* __restrict__ xi,
                                            const float* __restrict__ cosT, const float* __restrict__ sinT,
                                            float* __restrict__ kv) {
    const int b = blockIdx.x / NHEADS, h = blockIdx.x % NHEADS;
    __shared__ float ks[64][33];
    __shared__ float vs[64][33];
    const int tid = threadIdx.x;
    const int e0 = (tid & 15) * 2;
    const int d0 = (tid >> 4) * 2;
    float acc00 = 0.f, acc01 = 0.f, acc10 = 0.f, acc11 = 0.f;
    for (int n0 = 0; n0 < L_TOK; n0 += 64) {
#pragma unroll
        for (int j = 0; j < 4; ++j) {           // 1024 rope pairs
            int pi = tid + j * 256;
            int tn = pi >> 4;
            int pd = pi & 15;
            int n = n0 + tn;
            const float* kp = kbuf + ((size_t)(b * L_TOK + n)) * DIM + h * 32 + pd * 2;
            float ka = kp[0], kb2 = kp[1];
            float cs = cosT[n * 192 + h * 16 + pd];
            float sn = sinT[n * 192 + h * 16 + pd];
            ks[tn][pd * 2]     = cs * ka - sn * kb2;
            ks[tn][pd * 2 + 1] = sn * ka + cs * kb2;
        }
#pragma unroll
        for (int j = 0; j < 8; ++j) {           // 2048 v elems
            int vi = tid + j * 256;
            int tn = vi >> 5;
            int d = vi & 31;
            vs[tn][d] = xi[((size_t)(b * L_TOK + n0 + tn)) * DIM + h * 32 + d];
        }
        __syncthreads();
#pragma unroll 8
        for (int n = 0; n < 64; ++n) {
            float k0v = ks[n][d0], k1v = ks[n][d0 + 1];
            float v0 = vs[n][e0], v1 = vs[n][e0 + 1];
            acc00 = fmaf(k0v, v0, acc00);
            acc01 = fmaf(k0v, v1, acc01);
            acc10 = fmaf(k1v, v0, acc10);
            acc11 = fmaf(k1v, v1, acc11);
        }
        __syncthreads();
    }
    const float inv = 1.0f / (float)L_TOK;
    float* o = kv + ((size_t)blockIdx.x * 32 + d0) * 32 + e0;
    o[0] = acc00 * inv; o[1] = acc01 * inv;
    o[32] = acc10 * inv; o[33] = acc11 * inv;
}

// ---------------- att[b,n,c] = z(b,h,n) * sum_d rope(q)[n,h,d] * kv[b,h,d,e] ----------------
__global__ __launch_bounds__(384) void att_k(const float* __restrict__ q, const float* __restrict__ kv,
                                             const float* __restrict__ km,
                                             const float* __restrict__ cosT, const float* __restrict__ sinT,
                                             float* __restrict__ out) {
    __shared__ float kvs[NHEADS * 32 * 32];   // 48 KB
    __shared__ float kms[DIM];
    __shared__ float sq[DIM];
    __shared__ float sqr[DIM];
    const int b = blockIdx.x / 48;
    const int chunk = blockIdx.x % 48;
    const int tid = threadIdx.x;
    for (int i = tid; i < NHEADS * 1024; i += 384) kvs[i] = kv[(size_t)b * (NHEADS * 1024) + i];
    kms[tid] = km[b * DIM + tid];
    __syncthreads();
    const int h = tid >> 5, e = tid & 31;
    const int p = tid >> 1;
    const float* kvh = &kvs[h * 1024];
    for (int ni = 0; ni < 48; ++ni) {
        const int n = chunk * 48 + ni;
        const float qv = q[((size_t)(b * L_TOK + n)) * DIM + tid];
        sq[tid] = qv;
        __syncthreads();
        float a = sq[tid & ~1], bb = sq[tid | 1];
        float cs = cosT[n * 192 + p], sn = sinT[n * 192 + p];
        sqr[tid] = (tid & 1) ? fmaf(sn, a, cs * bb) : fmaf(cs, a, -sn * bb);
        float zp = qv * kms[tid];
#pragma unroll
        for (int o = 16; o > 0; o >>= 1) zp += __shfl_xor(zp, o, 32);
        const float z = 1.0f / (zp + 1e-6f);
        __syncthreads();
        float dot = 0.f;
        const float* qrh = &sqr[h * 32];
#pragma unroll 8
        for (int d = 0; d < 32; ++d) dot = fmaf(qrh[d], kvh[d * 32 + e], dot);
        out[((size_t)(b * L_TOK + n)) * DIM + tid] = z * dot;
        __syncthreads();
    }
}

// ---------------- elementwise multiply -> bf16 ----------------
__global__ __launch_bounds__(256) void mulbf_k(const float* __restrict__ a, const float* __restrict__ b,
                                               u16* __restrict__ o) {
    int i = blockIdx.x * 256 + threadIdx.x;     // grid covers nb*UNITB/4 exactly
    float4 x = ((const float4*)a)[i];
    float4 y = ((const float4*)b)[i];
    ushort4 r;
    r.x = f2bf(x.x * y.x); r.y = f2bf(x.y * y.y); r.z = f2bf(x.z * y.z); r.w = f2bf(x.w * y.w);
    ((ushort4*)o)[i] = r;
}

extern "C" void kernel_launch(void* const* d_in, const int* in_sizes, int n_in,
                              void* d_out, int out_size, void* d_ws, size_t ws_size,
                              hipStream_t stream) {
    const float* x       = (const float*)d_in[0];
    const float* cpe1_w  = (const float*)d_in[3];
    const float* cpe1_b  = (const float*)d_in[4];
    const float* norm1_w = (const float*)d_in[5];
    const float* norm1_b = (const float*)d_in[6];
    const float* in_w    = (const float*)d_in[7];
    const float* in_b    = (const float*)d_in[8];
    const float* act_w   = (const float*)d_in[9];
    const float* act_b   = (const float*)d_in[10];
    const float* dwc_w   = (const float*)d_in[11];
    const float* dwc_b   = (const float*)d_in[12];
    const float* qk_w    = (const float*)d_in[13];
    const float* qk_b    = (const float*)d_in[14];
    const float* lepe_w  = (const float*)d_in[15];
    const float* lepe_b  = (const float*)d_in[16];
    const float* outp_w  = (const float*)d_in[17];
    const float* outp_b  = (const float*)d_in[18];
    const float* cpe2_w  = (const float*)d_in[19];
    const float* cpe2_b  = (const float*)d_in[20];
    const float* norm2_w = (const float*)d_in[21];
    const float* norm2_b = (const float*)d_in[22];
    const float* fc1_w   = (const float*)d_in[23];
    const float* fc1_b   = (const float*)d_in[24];
    const float* fc2_w   = (const float*)d_in[25];
    const float* fc2_b   = (const float*)d_in[26];
    float* out = (float*)d_out;

    float* ws = (float*)d_ws;
    const size_t TAB = (size_t)L_TOK * 192;                      // 442368 floats per table
    // small region: cos, sin, km, part, kv, bf16 weights
    const size_t NW_IN = 147456, NW_QK = 294912, NW_FC = 589824;
    const size_t WBF_U16 = NW_IN * 3 + NW_QK + NW_FC * 2;        // 1,916,928 u16
    const size_t SMALL = 2 * TAB + (size_t)BATCH * DIM + 9 * (size_t)BATCH * DIM
                       + (size_t)BATCH * NHEADS * 1024 + WBF_U16 / 2;
    float* cosT = ws;
    float* sinT = cosT + TAB;
    float* km   = sinT + TAB;
    float* part = km + (size_t)BATCH * DIM;
    float* kvb  = part + 9 * (size_t)BATCH * DIM;
    u16*   wb_in  = (u16*)(kvb + (size_t)BATCH * NHEADS * 1024);
    u16*   wb_act = wb_in + NW_IN;
    u16*   wb_qk  = wb_act + NW_IN;
    u16*   wb_out = wb_qk + NW_QK;
    u16*   wb_fc1 = wb_out + NW_IN;
    u16*   wb_fc2 = wb_fc1 + NW_FC;
    float* gbuf = ws + SMALL;                                    // 4.5 group-units follow

    // pick largest batch-group size (4 f32 units + 0.5 unit bf16 xi copy per group)
    const size_t avail = (ws_size / 4 > SMALL) ? (ws_size / 4 - SMALL) : 0;
    int nb = 0;
    for (int cand = BATCH; cand >= 1; cand >>= 1)
        if (9 * (size_t)cand * UNITB / 2 <= avail) { nb = cand; break; }
    if (nb == 0) {
        sentinel_k<<<1, 1, 0, stream>>>(out, (float)(ws_size >> 20));
        return;
    }

    // per-launch weight conversion (graph-safe, deterministic)
    cvtw_k<<<(int)(NW_IN / 1024), 256, 0, stream>>>(in_w, wb_in);
    cvtw_k<<<(int)(NW_IN / 1024), 256, 0, stream>>>(act_w, wb_act);
    cvtw_k<<<(int)(NW_QK / 1024), 256, 0, stream>>>(qk_w, wb_qk);
    cvtw_k<<<(int)(NW_IN / 1024), 256, 0, stream>>>(outp_w, wb_out);
    cvtw_k<<<(int)(NW_FC / 1024), 256, 0, stream>>>(fc1_w, wb_fc1);
    cvtw_k<<<(int)(NW_FC / 1024), 256, 0, stream>>>(fc2_w, wb_fc2);
    rope_tab_k<<<(int)((TAB + 255) / 256), 256, 0, stream>>>(cosT, sinT);

    for (int b0 = 0; b0 < BATCH; b0 += nb) {
        const size_t goff = (size_t)b0 * UNITB;
        const size_t GU   = (size_t)nb * UNITB;
        float* W0 = gbuf;             // x1 / x3
        float* W1 = gbuf + GU;        // xn(bf16) / q(f32) / ao(bf16) / xn2(bf16)
        float* W2 = gbuf + 2 * GU;    // xi0 / act_res / x2 / h(bf16)
        float* W3 = gbuf + 3 * GU;    // xi (f32)
        u16*   Wb = (u16*)(gbuf + 4 * GU);   // xi (bf16), GU u16
        float* O  = out + goff;       // k / att / final out
        const float* Xg = x + goff;

        const int EW_GRID = (int)(GU / 256);
        const dim3 G384(3, nb * 18);

        // x1 = x + dwconv(x, cpe1)
        dwconv_k<<<EW_GRID, 256, 0, stream>>>(Xg, cpe1_w, cpe1_b, W0, nullptr, 0);
        // xn = LN(x1) -> bf16
        ln_k<<<nb * 576, 256, 0, stream>>>(W0, norm1_w, norm1_b, (u16*)W1);
        // xi0 = xn @ in_proj^T + b  (f32)
        gemm_bf16<<<G384, 256, 0, stream>>>((u16*)W1, DIM, wb_in, DIM, in_b, nullptr, W2, nullptr, DIM, DIM, M_BIAS);
        // xi = silu(dwconv(xi0, dwc)) -> f32 W3 + bf16 Wb
        dwconv_k<<<EW_GRID, 256, 0, stream>>>(W2, dwc_w, dwc_b, W3, Wb, 1);
        // act_res = silu(xn @ act_proj^T + b)  (f32)
        gemm_bf16<<<G384, 256, 0, stream>>>((u16*)W1, DIM, wb_act, DIM, act_b, nullptr, W2, nullptr, DIM, DIM, M_SILU);
        // q = elu(xi @ qk_w[:384]^T + b[:384]) + 1 -> W1 (f32)
        gemm_bf16<<<G384, 256, 0, stream>>>(Wb, DIM, wb_qk, DIM, qk_b, nullptr, W1, nullptr, DIM, DIM, M_ELU1);
        // k = elu(xi @ qk_w[384:]^T + b[384:]) + 1 -> O (f32)
        gemm_bf16<<<G384, 256, 0, stream>>>(Wb, DIM, wb_qk + (size_t)DIM * DIM, DIM, qk_b + DIM,
                                            nullptr, O, nullptr, DIM, DIM, M_ELU1);
        // kmean over k
        kmean_part_k<<<dim3(nb, 9), 384, 0, stream>>>(O, part, nb);
        kmean_fin_k<<<nb, 384, 0, stream>>>(part, km, nb);
        // kv state from rope(k), v=xi
        kv_k<<<nb * NHEADS, 256, 0, stream>>>(O, W3, cosT, sinT, kvb);
        // att -> O (overwrites k)
        att_k<<<nb * 48, 384, 0, stream>>>(W1, kvb, km, cosT, sinT, O);
        // att += dwconv(xi, lepe)
        dwconv_k<<<EW_GRID, 256, 0, stream>>>(W3, lepe_w, lepe_b, O, nullptr, 2);
        // ao = att * act_res -> W1 (bf16)
        mulbf_k<<<(int)(GU / 4 / 256), 256, 0, stream>>>(O, W2, (u16*)W1);
        // x2 = x1 + ao @ out_proj^T + b -> W2 (f32)
        gemm_bf16<<<G384, 256, 0, stream>>>((u16*)W1, DIM, wb_out, DIM, outp_b, W0, W2, nullptr, DIM, DIM, M_RES);
        // x3 = x2 + dwconv(x2, cpe2) -> W0
        dwconv_k<<<EW_GRID, 256, 0, stream>>>(W2, cpe2_w, cpe2_b, W0, nullptr, 0);
        // xn2 = LN(x3) -> W1 (bf16)
        ln_k<<<nb * 576, 256, 0, stream>>>(W0, norm2_w, norm2_b, (u16*)W1);
        // MLP in 4 chunks of 384: O = x3 + gelu(xn2@fc1^T)@fc2^T + b2
        for (int c = 0; c < 4; ++c) {
            // h_c = gelu(xn2 @ fc1_c^T + b) -> W2 (bf16)
            gemm_bf16<<<G384, 256, 0, stream>>>((u16*)W1, DIM, wb_fc1 + (size_t)c * 384 * DIM, DIM,
                                                fc1_b + c * 384, nullptr, nullptr, (u16*)W2, DIM, DIM, M_GELU);
            // O (+)= h_c @ fc2_c^T (+ b2 + x3 on first chunk)
            gemm_bf16<<<G384, 256, 0, stream>>>((u16*)W2, DIM, wb_fc2 + c * 384, 1536,
                                                (c == 0) ? fc2_b : nullptr,
                                                (c == 0) ? W0 : nullptr,
                                                O, nullptr, DIM, DIM, (c == 0) ? M_RES : M_ACC);
        }
    }
}

// Round 4
// 956.808 us; speedup vs baseline: 3.2064x; 1.6147x over previous
//
#include <hip/hip_runtime.h>
#include <math.h>

// MLLA block, round 4: float4 column-sliding dwconv (+lepe*act fusion),
// un-chunked MLP GEMMs, bf16-MFMA GEMMs. B=16, L=2304 (48x48), D=384.

#define L_TOK 2304
#define DIM   384
#define NHEADS 12
#define BATCH 16
#define HIMG  48
#define WIMG  48
#define UNITB ((size_t)L_TOK * DIM)    // 884,736 floats per batch

typedef unsigned short u16;
typedef __attribute__((ext_vector_type(8))) short bf16x8;
typedef __attribute__((ext_vector_type(4))) float f32x4;

enum { M_BIAS = 0, M_SILU = 1, M_ELU1 = 2, M_GELU = 3, M_RES = 4 };
enum { DW_RES = 0, DW_SILU = 1, DW_LEPE = 3 };

__device__ __forceinline__ float siluf(float x) { return x / (1.0f + expf(-x)); }
__device__ __forceinline__ float geluf(float x) { return 0.5f * x * (1.0f + erff(x * 0.70710678118654752f)); }
__device__ __forceinline__ u16 f2bf(float f) {   // RNE f32->bf16
    unsigned u = __float_as_uint(f);
    u += 0x7fffu + ((u >> 16) & 1u);
    return (u16)(u >> 16);
}

__global__ void sentinel_k(float* out, float v) { out[0] = v; }

// ---------------- weight f32 -> bf16 (n multiple of 1024) ----------------
__global__ __launch_bounds__(256) void cvtw_k(const float* __restrict__ src, u16* __restrict__ dst) {
    int i = blockIdx.x * 256 + threadIdx.x;
    float4 v = ((const float4*)src)[i];
    ushort4 o;
    o.x = f2bf(v.x); o.y = f2bf(v.y); o.z = f2bf(v.z); o.w = f2bf(v.w);
    ((ushort4*)dst)[i] = o;
}

// ---------------- RoPE tables: cos/sin[(h*48+w)*192 + p] ----------------
__global__ __launch_bounds__(256) void rope_tab_k(float* __restrict__ cosT, float* __restrict__ sinT) {
    int i = blockIdx.x * 256 + threadIdx.x;
    if (i >= L_TOK * 192) return;
    int n = i / 192, p = i % 192;
    int h = n / WIMG, w = n % WIMG;
    int j = (p < 96) ? p : p - 96;
    float pos = (p < 96) ? (float)h : (float)w;
    float theta = expf(-(float)j * (9.210340371976184f / 96.0f));  // 10000^(-j/96)
    float ang = pos * theta;
    cosT[i] = cosf(ang);
    sinT[i] = sinf(ang);
}

// ---------------- depthwise 3x3 conv, float4 column-sliding ----------------
// grid (18, nb*4): 4 h-strips of 12 rows. thread = (w, channel-quad) column.
// DW_RES : outf = src + conv(src)
// DW_SILU: r = silu(conv(src)); outf = r; outb = bf16(r)
// DW_LEPE: outb = bf16((att + conv(src)) * act)
#define FMA4(s, a, ww) { s.x = fmaf(a.x, ww.x, s.x); s.y = fmaf(a.y, ww.y, s.y); \
                         s.z = fmaf(a.z, ww.z, s.z); s.w = fmaf(a.w, ww.w, s.w); }
__global__ __launch_bounds__(256) void dwconv2_k(const float* __restrict__ src,
                                                 const float* __restrict__ wgt,
                                                 const float* __restrict__ bias,
                                                 const float* __restrict__ att,
                                                 const float* __restrict__ act,
                                                 float* __restrict__ outf,
                                                 u16* __restrict__ outb, int mode) {
    const int col = blockIdx.x * 256 + threadIdx.x;   // 0..4607 = w*96 + cg
    const int strip = blockIdx.y & 3;
    const int b = blockIdx.y >> 2;
    const int cg = col % 96, w = col / 96;
    const int rs = WIMG * DIM;                        // row stride (floats)
    const size_t ibase = (size_t)b * UNITB + (size_t)w * DIM + cg * 4;
    const float* srcb = src + ibase;
    const float4 z4 = {0.f, 0.f, 0.f, 0.f};

    float4 w9[9];
#pragma unroll
    for (int t = 0; t < 9; ++t) {
        const int c = cg * 4;
        w9[t] = (float4){wgt[(c + 0) * 9 + t], wgt[(c + 1) * 9 + t],
                         wgt[(c + 2) * 9 + t], wgt[(c + 3) * 9 + t]};
    }
    const float4 bv = ((const float4*)bias)[cg];

    float4 A0, A1, A2, B0, B1, B2, C0, C1, C2;
    auto ldrow = [&](int hh, float4& L0, float4& L1, float4& L2) {
        if ((unsigned)hh >= (unsigned)HIMG) { L0 = z4; L1 = z4; L2 = z4; return; }
        const float* p = srcb + (size_t)hh * rs;
        L0 = (w > 0)        ? *(const float4*)(p - DIM) : z4;
        L1 = *(const float4*)p;
        L2 = (w < WIMG - 1) ? *(const float4*)(p + DIM) : z4;
    };
    const int h0 = strip * 12;
    ldrow(h0 - 1, A0, A1, A2);
    ldrow(h0,     B0, B1, B2);
    for (int h = h0; h < h0 + 12; ++h) {
        ldrow(h + 1, C0, C1, C2);
        float4 s = bv;
        FMA4(s, A0, w9[0]); FMA4(s, A1, w9[1]); FMA4(s, A2, w9[2]);
        FMA4(s, B0, w9[3]); FMA4(s, B1, w9[4]); FMA4(s, B2, w9[5]);
        FMA4(s, C0, w9[6]); FMA4(s, C1, w9[7]); FMA4(s, C2, w9[8]);
        const size_t idx = ibase + (size_t)h * rs;
        if (mode == DW_RES) {
            s.x += B1.x; s.y += B1.y; s.z += B1.z; s.w += B1.w;
            *(float4*)(outf + idx) = s;
        } else if (mode == DW_SILU) {
            float4 r = {siluf(s.x), siluf(s.y), siluf(s.z), siluf(s.w)};
            *(float4*)(outf + idx) = r;
            ushort4 ob = {f2bf(r.x), f2bf(r.y), f2bf(r.z), f2bf(r.w)};
            *(ushort4*)(outb + idx) = ob;
        } else {  // DW_LEPE
            float4 a4 = *(const float4*)(att + idx);
            float4 m4 = *(const float4*)(act + idx);
            ushort4 ob = {f2bf((a4.x + s.x) * m4.x), f2bf((a4.y + s.y) * m4.y),
                          f2bf((a4.z + s.z) * m4.z), f2bf((a4.w + s.w) * m4.w)};
            *(ushort4*)(outb + idx) = ob;
        }
        A0 = B0; A1 = B1; A2 = B2;
        B0 = C0; B1 = C1; B2 = C2;
    }
}

// ---------------- LayerNorm over last dim (384) -> bf16, one wave per row ----------------
__global__ __launch_bounds__(256) void ln_k(const float* __restrict__ in,
                                            const float* __restrict__ w,
                                            const float* __restrict__ b,
                                            u16* __restrict__ out) {
    const int row = blockIdx.x * 4 + (threadIdx.x >> 6);
    const int lane = threadIdx.x & 63;
    const float* x = in + (size_t)row * DIM;
    float v[6];
    float s = 0.f;
#pragma unroll
    for (int i = 0; i < 6; ++i) { v[i] = x[lane + i * 64]; s += v[i]; }
#pragma unroll
    for (int o = 32; o > 0; o >>= 1) s += __shfl_xor(s, o, 64);
    const float mean = s * (1.0f / DIM);
    float q = 0.f;
#pragma unroll
    for (int i = 0; i < 6; ++i) { float d = v[i] - mean; q = fmaf(d, d, q); }
#pragma unroll
    for (int o = 32; o > 0; o >>= 1) q += __shfl_xor(q, o, 64);
    const float rs = 1.0f / sqrtf(q * (1.0f / DIM) + 1e-5f);
    u16* o2 = out + (size_t)row * DIM;
#pragma unroll
    for (int i = 0; i < 6; ++i) {
        int d = lane + i * 64;
        o2[d] = f2bf(fmaf((v[i] - mean) * rs, w[d], b[d]));
    }
}

// ---------------- bf16 MFMA GEMM: C[M,N] = A[M,K]bf16 @ Wt[N,K]bf16^T (+epilogue) ----------------
// 128x128 tile, BK=32, 256 threads (4 waves, each 64x64 = 4x4 16x16 fragments).
__global__ __launch_bounds__(256) void gemm_bf16(const u16* __restrict__ A, int lda,
                                                 const u16* __restrict__ Wt, int ldw,
                                                 const float* __restrict__ bias,
                                                 const float* __restrict__ res,
                                                 float* __restrict__ Cf, u16* __restrict__ Cb,
                                                 int ldc, int K, int mode) {
    __shared__ u16 As[128 * 32];
    __shared__ u16 Bs[128 * 32];
    const int tid = threadIdx.x;
    const int l = tid & 63;
    const int w = tid >> 6;
    const int m0 = blockIdx.y * 128, n0 = blockIdx.x * 128;
    const int fr = l & 15, kb = l >> 4;          // fragment row, k-block
    const int wm = (w >> 1) * 64, wn = (w & 1) * 64;
    f32x4 acc[4][4];
#pragma unroll
    for (int i = 0; i < 4; ++i)
#pragma unroll
        for (int j = 0; j < 4; ++j) acc[i][j] = (f32x4){0.f, 0.f, 0.f, 0.f};

    for (int k0 = 0; k0 < K; k0 += 32) {
#pragma unroll
        for (int i = 0; i < 2; ++i) {
            const int chb = i * 256 + w * 64;    // wave-uniform chunk base
            const int ch = chb + l;              // per-lane chunk
            const u16* ga = A + (size_t)(m0 + (ch >> 2)) * lda + (k0 + (ch & 3) * 8);
            __builtin_amdgcn_global_load_lds((const __attribute__((address_space(1))) void*)ga,
                                             (__attribute__((address_space(3))) void*)(As + chb * 8),
                                             16, 0, 0);
            const u16* gb = Wt + (size_t)(n0 + (ch >> 2)) * ldw + (k0 + (ch & 3) * 8);
            __builtin_amdgcn_global_load_lds((const __attribute__((address_space(1))) void*)gb,
                                             (__attribute__((address_space(3))) void*)(Bs + chb * 8),
                                             16, 0, 0);
        }
        asm volatile("s_waitcnt vmcnt(0)" ::: "memory");
        __syncthreads();
        bf16x8 af[4], bfr[4];
#pragma unroll
        for (int mi = 0; mi < 4; ++mi) af[mi] = *(const bf16x8*)&As[(wm + mi * 16 + fr) * 32 + kb * 8];
#pragma unroll
        for (int ni = 0; ni < 4; ++ni) bfr[ni] = *(const bf16x8*)&Bs[(wn + ni * 16 + fr) * 32 + kb * 8];
#pragma unroll
        for (int mi = 0; mi < 4; ++mi)
#pragma unroll
            for (int ni = 0; ni < 4; ++ni)
                acc[mi][ni] = __builtin_amdgcn_mfma_f32_16x16x32_bf16(af[mi], bfr[ni], acc[mi][ni], 0, 0, 0);
        __syncthreads();
    }
    const int orow = (l >> 4) * 4, ocol = l & 15;    // C/D mapping [m89-verified]
#pragma unroll
    for (int mi = 0; mi < 4; ++mi) {
#pragma unroll
        for (int ni = 0; ni < 4; ++ni) {
            const int n = n0 + wn + ni * 16 + ocol;
            const float bv = bias[n];
#pragma unroll
            for (int r = 0; r < 4; ++r) {
                const int m = m0 + wm + mi * 16 + orow + r;
                float v = acc[mi][ni][r] + bv;
                if (mode == M_SILU)      v = siluf(v);
                else if (mode == M_ELU1) v = (v > 0.f) ? (v + 1.f) : expf(v);
                else if (mode == M_GELU) v = geluf(v);
                const size_t oi = (size_t)m * ldc + n;
                if (mode == M_RES)  v += res[oi];
                if (mode == M_GELU) Cb[oi] = f2bf(v);
                else                Cf[oi] = v;
            }
        }
    }
}

// ---------------- kmean: column mean of k (M x 384 layout), two-stage ----------------
__global__ __launch_bounds__(384) void kmean_part_k(const float* __restrict__ kbuf, float* __restrict__ part, int nb) {
    const int b = blockIdx.x, chunk = blockIdx.y;   // nb x 9
    const int c = threadIdx.x;
    const float* p = kbuf + ((size_t)(b * L_TOK + chunk * 256)) * DIM + c;
    float s = 0.f;
    for (int n = 0; n < 256; ++n) s += p[(size_t)n * DIM];
    part[(size_t)(chunk * nb + b) * DIM + c] = s;
}

__global__ __launch_bounds__(384) void kmean_fin_k(const float* __restrict__ part, float* __restrict__ km, int nb) {
    const int b = blockIdx.x, c = threadIdx.x;
    float s = 0.f;
#pragma unroll
    for (int ch = 0; ch < 9; ++ch) s += part[(size_t)(ch * nb + b) * DIM + c];
    km[b * DIM + c] = s * (1.0f / L_TOK);
}

// ---------------- kv[b,h,d,e] = (1/L) sum_n rope(k)[n,d] * v[n,e] ----------------
__global__ __launch_bounds__(256) void kv_k(const float* __restrict__ kbuf, const float* __restrict__ xi,
                                            const float* __restrict__ cosT, const float* __restrict__ sinT,
                                            float* __restrict__ kv) {
    const int b = blockIdx.x / NHEADS, h = blockIdx.x % NHEADS;
    __shared__ float ks[64][33];
    __shared__ float vs[64][33];
    const int tid = threadIdx.x;
    const int e0 = (tid & 15) * 2;
    const int d0 = (tid >> 4) * 2;
    float acc00 = 0.f, acc01 = 0.f, acc10 = 0.f, acc11 = 0.f;
    for (int n0 = 0; n0 < L_TOK; n0 += 64) {
#pragma unroll
        for (int j = 0; j < 4; ++j) {           // 1024 rope pairs
            int pi = tid + j * 256;
            int tn = pi >> 4;
            int pd = pi & 15;
            int n = n0 + tn;
            const float* kp = kbuf + ((size_t)(b * L_TOK + n)) * DIM + h * 32 + pd * 2;
            float ka = kp[0], kb2 = kp[1];
            float cs = cosT[n * 192 + h * 16 + pd];
            float sn = sinT[n * 192 + h * 16 + pd];
            ks[tn][pd * 2]     = cs * ka - sn * kb2;
            ks[tn][pd * 2 + 1] = sn * ka + cs * kb2;
        }
#pragma unroll
        for (int j = 0; j < 8; ++j) {           // 2048 v elems
            int vi = tid + j * 256;
            int tn = vi >> 5;
            int d = vi & 31;
            vs[tn][d] = xi[((size_t)(b * L_TOK + n0 + tn)) * DIM + h * 32 + d];
        }
        __syncthreads();
#pragma unroll 8
        for (int n = 0; n < 64; ++n) {
            float k0v = ks[n][d0], k1v = ks[n][d0 + 1];
            float v0 = vs[n][e0], v1 = vs[n][e0 + 1];
            acc00 = fmaf(k0v, v0, acc00);
            acc01 = fmaf(k0v, v1, acc01);
            acc10 = fmaf(k1v, v0, acc10);
            acc11 = fmaf(k1v, v1, acc11);
        }
        __syncthreads();
    }
    const float inv = 1.0f / (float)L_TOK;
    float* o = kv + ((size_t)blockIdx.x * 32 + d0) * 32 + e0;
    o[0] = acc00 * inv; o[1] = acc01 * inv;
    o[32] = acc10 * inv; o[33] = acc11 * inv;
}

// ---------------- att[b,n,c] = z(b,h,n) * sum_d rope(q)[n,h,d] * kv[b,h,d,e] ----------------
__global__ __launch_bounds__(384) void att_k(const float* __restrict__ q, const float* __restrict__ kv,
                                             const float* __restrict__ km,
                                             const float* __restrict__ cosT, const float* __restrict__ sinT,
                                             float* __restrict__ out) {
    __shared__ float kvs[NHEADS * 32 * 32];   // 48 KB
    __shared__ float kms[DIM];
    __shared__ float sq[DIM];
    __shared__ float sqr[DIM];
    const int b = blockIdx.x / 48;
    const int chunk = blockIdx.x % 48;
    const int tid = threadIdx.x;
    for (int i = tid; i < NHEADS * 1024; i += 384) kvs[i] = kv[(size_t)b * (NHEADS * 1024) + i];
    kms[tid] = km[b * DIM + tid];
    __syncthreads();
    const int h = tid >> 5, e = tid & 31;
    const int p = tid >> 1;
    const float* kvh = &kvs[h * 1024];
    for (int ni = 0; ni < 48; ++ni) {
        const int n = chunk * 48 + ni;
        const float qv = q[((size_t)(b * L_TOK + n)) * DIM + tid];
        sq[tid] = qv;
        __syncthreads();
        float a = sq[tid & ~1], bb = sq[tid | 1];
        float cs = cosT[n * 192 + p], sn = sinT[n * 192 + p];
        sqr[tid] = (tid & 1) ? fmaf(sn, a, cs * bb) : fmaf(cs, a, -sn * bb);
        float zp = qv * kms[tid];
#pragma unroll
        for (int o = 16; o > 0; o >>= 1) zp += __shfl_xor(zp, o, 32);
        const float z = 1.0f / (zp + 1e-6f);
        __syncthreads();
        float dot = 0.f;
        const float* qrh = &sqr[h * 32];
#pragma unroll 8
        for (int d = 0; d < 32; ++d) dot = fmaf(qrh[d], kvh[d * 32 + e], dot);
        out[((size_t)(b * L_TOK + n)) * DIM + tid] = z * dot;
        __syncthreads();
    }
}

extern "C" void kernel_launch(void* const* d_in, const int* in_sizes, int n_in,
                              void* d_out, int out_size, void* d_ws, size_t ws_size,
                              hipStream_t stream) {
    const float* x       = (const float*)d_in[0];
    const float* cpe1_w  = (const float*)d_in[3];
    const float* cpe1_b  = (const float*)d_in[4];
    const float* norm1_w = (const float*)d_in[5];
    const float* norm1_b = (const float*)d_in[6];
    const float* in_w    = (const float*)d_in[7];
    const float* in_b    = (const float*)d_in[8];
    const float* act_w   = (const float*)d_in[9];
    const float* act_b   = (const float*)d_in[10];
    const float* dwc_w   = (const float*)d_in[11];
    const float* dwc_b   = (const float*)d_in[12];
    const float* qk_w    = (const float*)d_in[13];
    const float* qk_b    = (const float*)d_in[14];
    const float* lepe_w  = (const float*)d_in[15];
    const float* lepe_b  = (const float*)d_in[16];
    const float* outp_w  = (const float*)d_in[17];
    const float* outp_b  = (const float*)d_in[18];
    const float* cpe2_w  = (const float*)d_in[19];
    const float* cpe2_b  = (const float*)d_in[20];
    const float* norm2_w = (const float*)d_in[21];
    const float* norm2_b = (const float*)d_in[22];
    const float* fc1_w   = (const float*)d_in[23];
    const float* fc1_b   = (const float*)d_in[24];
    const float* fc2_w   = (const float*)d_in[25];
    const float* fc2_b   = (const float*)d_in[26];
    float* out = (float*)d_out;

    float* ws = (float*)d_ws;
    const size_t TAB = (size_t)L_TOK * 192;
    const size_t NW_IN = 147456, NW_QK = 294912, NW_FC = 589824;
    const size_t WBF_U16 = NW_IN * 3 + NW_QK + NW_FC * 2;
    const size_t SMALL = 2 * TAB + (size_t)BATCH * DIM + 9 * (size_t)BATCH * DIM
                       + (size_t)BATCH * NHEADS * 1024 + WBF_U16 / 2;
    float* cosT = ws;
    float* sinT = cosT + TAB;
    float* km   = sinT + TAB;
    float* part = km + (size_t)BATCH * DIM;
    float* kvb  = part + 9 * (size_t)BATCH * DIM;
    u16*   wb_in  = (u16*)(kvb + (size_t)BATCH * NHEADS * 1024);
    u16*   wb_act = wb_in + NW_IN;
    u16*   wb_qk  = wb_act + NW_IN;
    u16*   wb_out = wb_qk + NW_QK;
    u16*   wb_fc1 = wb_out + NW_IN;
    u16*   wb_fc2 = wb_fc1 + NW_FC;
    float* gbuf = ws + SMALL;

    // 4 f32 group-units + 0.5 unit bf16 xi copy per group (h spans W2+W3 in-place)
    const size_t avail = (ws_size / 4 > SMALL) ? (ws_size / 4 - SMALL) : 0;
    int nb = 0;
    for (int cand = BATCH; cand >= 1; cand >>= 1)
        if (9 * (size_t)cand * UNITB / 2 <= avail) { nb = cand; break; }
    if (nb == 0) {
        sentinel_k<<<1, 1, 0, stream>>>(out, (float)(ws_size >> 20));
        return;
    }

    cvtw_k<<<(int)(NW_IN / 1024), 256, 0, stream>>>(in_w, wb_in);
    cvtw_k<<<(int)(NW_IN / 1024), 256, 0, stream>>>(act_w, wb_act);
    cvtw_k<<<(int)(NW_QK / 1024), 256, 0, stream>>>(qk_w, wb_qk);
    cvtw_k<<<(int)(NW_IN / 1024), 256, 0, stream>>>(outp_w, wb_out);
    cvtw_k<<<(int)(NW_FC / 1024), 256, 0, stream>>>(fc1_w, wb_fc1);
    cvtw_k<<<(int)(NW_FC / 1024), 256, 0, stream>>>(fc2_w, wb_fc2);
    rope_tab_k<<<(int)((TAB + 255) / 256), 256, 0, stream>>>(cosT, sinT);

    for (int b0 = 0; b0 < BATCH; b0 += nb) {
        const size_t goff = (size_t)b0 * UNITB;
        const size_t GU   = (size_t)nb * UNITB;
        float* W0 = gbuf;             // x1 / x3
        float* W1 = gbuf + GU;        // xn(bf16) / q(f32) / ao(bf16) / xn2(bf16)
        float* W2 = gbuf + 2 * GU;    // xi0 / act_res / x2 / h(bf16, spans W2+W3)
        float* W3 = gbuf + 3 * GU;    // xi (f32)
        u16*   Wb = (u16*)(gbuf + 4 * GU);   // xi (bf16)
        float* O  = out + goff;       // k / att / final out
        const float* Xg = x + goff;

        const dim3 DWG(18, nb * 4);
        const dim3 G384(3, nb * 18), G1536(12, nb * 18);

        // x1 = x + dwconv(x, cpe1) -> W0
        dwconv2_k<<<DWG, 256, 0, stream>>>(Xg, cpe1_w, cpe1_b, nullptr, nullptr, W0, nullptr, DW_RES);
        // xn = LN(x1) -> W1 bf16
        ln_k<<<nb * 576, 256, 0, stream>>>(W0, norm1_w, norm1_b, (u16*)W1);
        // xi0 = xn @ in_proj^T + b -> W2 f32
        gemm_bf16<<<G384, 256, 0, stream>>>((u16*)W1, DIM, wb_in, DIM, in_b, nullptr, W2, nullptr, DIM, DIM, M_BIAS);
        // xi = silu(dwconv(xi0, dwc)) -> W3 f32 + Wb bf16
        dwconv2_k<<<DWG, 256, 0, stream>>>(W2, dwc_w, dwc_b, nullptr, nullptr, W3, Wb, DW_SILU);
        // act_res = silu(xn @ act_proj^T + b) -> W2 f32
        gemm_bf16<<<G384, 256, 0, stream>>>((u16*)W1, DIM, wb_act, DIM, act_b, nullptr, W2, nullptr, DIM, DIM, M_SILU);
        // q = elu(xi @ qk_w[:384]^T + b) + 1 -> W1 f32
        gemm_bf16<<<G384, 256, 0, stream>>>(Wb, DIM, wb_qk, DIM, qk_b, nullptr, W1, nullptr, DIM, DIM, M_ELU1);
        // k = elu(xi @ qk_w[384:]^T + b) + 1 -> O f32
        gemm_bf16<<<G384, 256, 0, stream>>>(Wb, DIM, wb_qk + (size_t)DIM * DIM, DIM, qk_b + DIM,
                                            nullptr, O, nullptr, DIM, DIM, M_ELU1);
        // kmean over k
        kmean_part_k<<<dim3(nb, 9), 384, 0, stream>>>(O, part, nb);
        kmean_fin_k<<<nb, 384, 0, stream>>>(part, km, nb);
        // kv state from rope(k), v=xi
        kv_k<<<nb * NHEADS, 256, 0, stream>>>(O, W3, cosT, sinT, kvb);
        // att -> O (overwrites k)
        att_k<<<nb * 48, 384, 0, stream>>>(W1, kvb, km, cosT, sinT, O);
        // ao = (att + dwconv(xi, lepe)) * act_res -> W1 bf16   [fused lepe+mul]
        dwconv2_k<<<DWG, 256, 0, stream>>>(W3, lepe_w, lepe_b, O, W2, nullptr, (u16*)W1, DW_LEPE);
        // x2 = x1 + ao @ out_proj^T + b -> W2 f32
        gemm_bf16<<<G384, 256, 0, stream>>>((u16*)W1, DIM, wb_out, DIM, outp_b, W0, W2, nullptr, DIM, DIM, M_RES);
        // x3 = x2 + dwconv(x2, cpe2) -> W0
        dwconv2_k<<<DWG, 256, 0, stream>>>(W2, cpe2_w, cpe2_b, nullptr, nullptr, W0, nullptr, DW_RES);
        // xn2 = LN(x3) -> W1 bf16
        ln_k<<<nb * 576, 256, 0, stream>>>(W0, norm2_w, norm2_b, (u16*)W1);
        // h = gelu(xn2 @ fc1^T + b) -> bf16, spans W2+W3 (113 MB at nb=16)
        gemm_bf16<<<G1536, 256, 0, stream>>>((u16*)W1, DIM, wb_fc1, DIM, fc1_b, nullptr,
                                             nullptr, (u16*)W2, 1536, DIM, M_GELU);
        // O = x3 + h @ fc2^T + b2
        gemm_bf16<<<G384, 256, 0, stream>>>((u16*)W2, 1536, wb_fc2, 1536, fc2_b, W0,
                                            O, nullptr, DIM, 1536, M_RES);
    }
}

// Round 5
// 850.613 us; speedup vs baseline: 3.6068x; 1.1248x over previous
//
#include <hip/hip_runtime.h>
#include <math.h>

// MLLA block, round 5: 2-phase double-buffered MFMA GEMM (counted vmcnt),
// bf16 intermediates off the residual chain. B=16, L=2304 (48x48), D=384.

#define L_TOK 2304
#define DIM   384
#define NHEADS 12
#define BATCH 16
#define HIMG  48
#define WIMG  48
#define UNITB ((size_t)L_TOK * DIM)    // 884,736 floats per batch

typedef unsigned short u16;
typedef __attribute__((ext_vector_type(8))) short bf16x8;
typedef __attribute__((ext_vector_type(4))) float f32x4;

enum { M_BIAS = 0, M_SILU = 1, M_ELU1 = 2, M_GELU = 3, M_RES = 4 };

__device__ __forceinline__ float siluf(float x) { return x / (1.0f + expf(-x)); }
__device__ __forceinline__ float geluf(float x) { return 0.5f * x * (1.0f + erff(x * 0.70710678118654752f)); }
__device__ __forceinline__ u16 f2bf(float f) {   // RNE f32->bf16
    unsigned u = __float_as_uint(f);
    u += 0x7fffu + ((u >> 16) & 1u);
    return (u16)(u >> 16);
}
__device__ __forceinline__ float bf2f(u16 u) { return __uint_as_float(((unsigned)u) << 16); }
__device__ __forceinline__ float4 bf2f4(ushort4 v) {
    return (float4){bf2f(v.x), bf2f(v.y), bf2f(v.z), bf2f(v.w)};
}

__global__ void sentinel_k(float* out, float v) { out[0] = v; }

// ---------------- weight f32 -> bf16 (n multiple of 1024) ----------------
__global__ __launch_bounds__(256) void cvtw_k(const float* __restrict__ src, u16* __restrict__ dst) {
    int i = blockIdx.x * 256 + threadIdx.x;
    float4 v = ((const float4*)src)[i];
    ushort4 o;
    o.x = f2bf(v.x); o.y = f2bf(v.y); o.z = f2bf(v.z); o.w = f2bf(v.w);
    ((ushort4*)dst)[i] = o;
}

// ---------------- RoPE tables: cos/sin[(h*48+w)*192 + p] ----------------
__global__ __launch_bounds__(256) void rope_tab_k(float* __restrict__ cosT, float* __restrict__ sinT) {
    int i = blockIdx.x * 256 + threadIdx.x;
    if (i >= L_TOK * 192) return;
    int n = i / 192, p = i % 192;
    int h = n / WIMG, w = n % WIMG;
    int j = (p < 96) ? p : p - 96;
    float pos = (p < 96) ? (float)h : (float)w;
    float theta = expf(-(float)j * (9.210340371976184f / 96.0f));  // 10000^(-j/96)
    float ang = pos * theta;
    cosT[i] = cosf(ang);
    sinT[i] = sinf(ang);
}

#define FMA4(s, a, ww) { s.x = fmaf(a.x, ww.x, s.x); s.y = fmaf(a.y, ww.y, s.y); \
                         s.z = fmaf(a.z, ww.z, s.z); s.w = fmaf(a.w, ww.w, s.w); }

// ---------------- depthwise 3x3 conv, f32 src, residual: out = src + conv(src) ----------------
__global__ __launch_bounds__(256) void dwconvf_k(const float* __restrict__ src,
                                                 const float* __restrict__ wgt,
                                                 const float* __restrict__ bias,
                                                 float* __restrict__ outf) {
    const int col = blockIdx.x * 256 + threadIdx.x;   // w*96 + cg
    const int strip = blockIdx.y & 3;
    const int b = blockIdx.y >> 2;
    const int cg = col % 96, w = col / 96;
    const int rs = WIMG * DIM;
    const size_t ibase = (size_t)b * UNITB + (size_t)w * DIM + cg * 4;
    const float* srcb = src + ibase;
    const float4 z4 = {0.f, 0.f, 0.f, 0.f};
    float4 w9[9];
#pragma unroll
    for (int t = 0; t < 9; ++t) {
        const int c = cg * 4;
        w9[t] = (float4){wgt[(c + 0) * 9 + t], wgt[(c + 1) * 9 + t],
                         wgt[(c + 2) * 9 + t], wgt[(c + 3) * 9 + t]};
    }
    const float4 bv = ((const float4*)bias)[cg];
    float4 A0, A1, A2, B0, B1, B2, C0, C1, C2;
    auto ldrow = [&](int hh, float4& L0, float4& L1, float4& L2) {
        if ((unsigned)hh >= (unsigned)HIMG) { L0 = z4; L1 = z4; L2 = z4; return; }
        const float* p = srcb + (size_t)hh * rs;
        L0 = (w > 0)        ? *(const float4*)(p - DIM) : z4;
        L1 = *(const float4*)p;
        L2 = (w < WIMG - 1) ? *(const float4*)(p + DIM) : z4;
    };
    const int h0 = strip * 12;
    ldrow(h0 - 1, A0, A1, A2);
    ldrow(h0,     B0, B1, B2);
    for (int h = h0; h < h0 + 12; ++h) {
        ldrow(h + 1, C0, C1, C2);
        float4 s = bv;
        FMA4(s, A0, w9[0]); FMA4(s, A1, w9[1]); FMA4(s, A2, w9[2]);
        FMA4(s, B0, w9[3]); FMA4(s, B1, w9[4]); FMA4(s, B2, w9[5]);
        FMA4(s, C0, w9[6]); FMA4(s, C1, w9[7]); FMA4(s, C2, w9[8]);
        const size_t idx = ibase + (size_t)h * rs;
        s.x += B1.x; s.y += B1.y; s.z += B1.z; s.w += B1.w;
        *(float4*)(outf + idx) = s;
        A0 = B0; A1 = B1; A2 = B2;
        B0 = C0; B1 = C1; B2 = C2;
    }
}

// ---------------- depthwise 3x3 conv, bf16 src ----------------
// mode 1 (SILU): out = bf16(silu(conv(src)))
// mode 3 (LEPE): out = bf16((att + conv(src)) * act)
__global__ __launch_bounds__(256) void dwconvb_k(const u16* __restrict__ src,
                                                 const float* __restrict__ wgt,
                                                 const float* __restrict__ bias,
                                                 const u16* __restrict__ att,
                                                 const u16* __restrict__ act,
                                                 u16* __restrict__ outb, int mode) {
    const int col = blockIdx.x * 256 + threadIdx.x;
    const int strip = blockIdx.y & 3;
    const int b = blockIdx.y >> 2;
    const int cg = col % 96, w = col / 96;
    const int rs = WIMG * DIM;
    const size_t ibase = (size_t)b * UNITB + (size_t)w * DIM + cg * 4;
    const u16* srcb = src + ibase;
    const float4 z4 = {0.f, 0.f, 0.f, 0.f};
    float4 w9[9];
#pragma unroll
    for (int t = 0; t < 9; ++t) {
        const int c = cg * 4;
        w9[t] = (float4){wgt[(c + 0) * 9 + t], wgt[(c + 1) * 9 + t],
                         wgt[(c + 2) * 9 + t], wgt[(c + 3) * 9 + t]};
    }
    const float4 bv = ((const float4*)bias)[cg];
    float4 A0, A1, A2, B0, B1, B2, C0, C1, C2;
    auto ldrow = [&](int hh, float4& L0, float4& L1, float4& L2) {
        if ((unsigned)hh >= (unsigned)HIMG) { L0 = z4; L1 = z4; L2 = z4; return; }
        const u16* p = srcb + (size_t)hh * rs;
        L0 = (w > 0)        ? bf2f4(*(const ushort4*)(p - DIM)) : z4;
        L1 = bf2f4(*(const ushort4*)p);
        L2 = (w < WIMG - 1) ? bf2f4(*(const ushort4*)(p + DIM)) : z4;
    };
    const int h0 = strip * 12;
    ldrow(h0 - 1, A0, A1, A2);
    ldrow(h0,     B0, B1, B2);
    for (int h = h0; h < h0 + 12; ++h) {
        ldrow(h + 1, C0, C1, C2);
        float4 s = bv;
        FMA4(s, A0, w9[0]); FMA4(s, A1, w9[1]); FMA4(s, A2, w9[2]);
        FMA4(s, B0, w9[3]); FMA4(s, B1, w9[4]); FMA4(s, B2, w9[5]);
        FMA4(s, C0, w9[6]); FMA4(s, C1, w9[7]); FMA4(s, C2, w9[8]);
        const size_t idx = ibase + (size_t)h * rs;
        ushort4 ob;
        if (mode == 1) {
            ob = (ushort4){f2bf(siluf(s.x)), f2bf(siluf(s.y)), f2bf(siluf(s.z)), f2bf(siluf(s.w))};
        } else {
            float4 a4 = bf2f4(*(const ushort4*)(att + idx));
            float4 m4 = bf2f4(*(const ushort4*)(act + idx));
            ob = (ushort4){f2bf((a4.x + s.x) * m4.x), f2bf((a4.y + s.y) * m4.y),
                           f2bf((a4.z + s.z) * m4.z), f2bf((a4.w + s.w) * m4.w)};
        }
        *(ushort4*)(outb + idx) = ob;
        A0 = B0; A1 = B1; A2 = B2;
        B0 = C0; B1 = C1; B2 = C2;
    }
}

// ---------------- LayerNorm over last dim (384) -> bf16, one wave per row ----------------
__global__ __launch_bounds__(256) void ln_k(const float* __restrict__ in,
                                            const float* __restrict__ w,
                                            const float* __restrict__ b,
                                            u16* __restrict__ out) {
    const int row = blockIdx.x * 4 + (threadIdx.x >> 6);
    const int lane = threadIdx.x & 63;
    const float* x = in + (size_t)row * DIM;
    float v[6];
    float s = 0.f;
#pragma unroll
    for (int i = 0; i < 6; ++i) { v[i] = x[lane + i * 64]; s += v[i]; }
#pragma unroll
    for (int o = 32; o > 0; o >>= 1) s += __shfl_xor(s, o, 64);
    const float mean = s * (1.0f / DIM);
    float q = 0.f;
#pragma unroll
    for (int i = 0; i < 6; ++i) { float d = v[i] - mean; q = fmaf(d, d, q); }
#pragma unroll
    for (int o = 32; o > 0; o >>= 1) q += __shfl_xor(q, o, 64);
    const float rs = 1.0f / sqrtf(q * (1.0f / DIM) + 1e-5f);
    u16* o2 = out + (size_t)row * DIM;
#pragma unroll
    for (int i = 0; i < 6; ++i) {
        int d = lane + i * 64;
        o2[d] = f2bf(fmaf((v[i] - mean) * rs, w[d], b[d]));
    }
}

// ---------------- stage one 128x32 bf16 tile pair via global_load_lds ----------------
__device__ __forceinline__ void stage_tile(const u16* __restrict__ A, int lda,
                                           const u16* __restrict__ Wt, int ldw,
                                           int m0, int n0, int k0,
                                           u16* As, u16* Bs, int w, int l) {
#pragma unroll
    for (int i = 0; i < 2; ++i) {
        const int chb = i * 256 + w * 64;    // wave-uniform chunk base
        const int ch = chb + l;              // per-lane chunk (16B)
        const u16* ga = A + (size_t)(m0 + (ch >> 2)) * lda + (k0 + (ch & 3) * 8);
        __builtin_amdgcn_global_load_lds((const __attribute__((address_space(1))) void*)ga,
                                         (__attribute__((address_space(3))) void*)(As + chb * 8),
                                         16, 0, 0);
        const u16* gb = Wt + (size_t)(n0 + (ch >> 2)) * ldw + (k0 + (ch & 3) * 8);
        __builtin_amdgcn_global_load_lds((const __attribute__((address_space(1))) void*)gb,
                                         (__attribute__((address_space(3))) void*)(Bs + chb * 8),
                                         16, 0, 0);
    }
}

// ---------------- bf16 MFMA GEMM, 2-phase double-buffered ----------------
// C[M,N] = A[M,K]bf16 @ Wt[N,K]bf16^T (+epilogue). 128x128 tile, BK=32, 4 waves.
// Out: bf16 if Cb!=null else f32 Cf.
__global__ __launch_bounds__(256) void gemm_bf16(const u16* __restrict__ A, int lda,
                                                 const u16* __restrict__ Wt, int ldw,
                                                 const float* __restrict__ bias,
                                                 const float* __restrict__ res,
                                                 float* __restrict__ Cf, u16* __restrict__ Cb,
                                                 int ldc, int K, int mode) {
    __shared__ u16 As[2][4096];
    __shared__ u16 Bs[2][4096];
    const int tid = threadIdx.x;
    const int l = tid & 63;
    const int w = tid >> 6;
    const int m0 = blockIdx.y * 128, n0 = blockIdx.x * 128;
    const int fr = l & 15, kb = l >> 4;
    const int wm = (w >> 1) * 64, wn = (w & 1) * 64;
    f32x4 acc[4][4];
#pragma unroll
    for (int i = 0; i < 4; ++i)
#pragma unroll
        for (int j = 0; j < 4; ++j) acc[i][j] = (f32x4){0.f, 0.f, 0.f, 0.f};

    const int nt = K >> 5;
    stage_tile(A, lda, Wt, ldw, m0, n0, 0, As[0], Bs[0], w, l);
    int cur = 0;
    for (int t = 0; t < nt; ++t) {
        if (t + 1 < nt) {
            stage_tile(A, lda, Wt, ldw, m0, n0, (t + 1) << 5, As[cur ^ 1], Bs[cur ^ 1], w, l);
            asm volatile("s_waitcnt vmcnt(4)" ::: "memory");   // tile t done; t+1's 4 stay in flight
        } else {
            asm volatile("s_waitcnt vmcnt(0)" ::: "memory");
        }
        __builtin_amdgcn_s_barrier();
        __builtin_amdgcn_sched_barrier(0);
        bf16x8 af[4], bfr[4];
#pragma unroll
        for (int mi = 0; mi < 4; ++mi) af[mi] = *(const bf16x8*)&As[cur][(wm + mi * 16 + fr) * 32 + kb * 8];
#pragma unroll
        for (int ni = 0; ni < 4; ++ni) bfr[ni] = *(const bf16x8*)&Bs[cur][(wn + ni * 16 + fr) * 32 + kb * 8];
#pragma unroll
        for (int mi = 0; mi < 4; ++mi)
#pragma unroll
            for (int ni = 0; ni < 4; ++ni)
                acc[mi][ni] = __builtin_amdgcn_mfma_f32_16x16x32_bf16(af[mi], bfr[ni], acc[mi][ni], 0, 0, 0);
        __builtin_amdgcn_sched_barrier(0);
        __builtin_amdgcn_s_barrier();     // protect buf[cur] from next iter's stage
        cur ^= 1;
    }
    const int orow = (l >> 4) * 4, ocol = l & 15;    // C/D mapping [m89-verified]
#pragma unroll
    for (int mi = 0; mi < 4; ++mi) {
#pragma unroll
        for (int ni = 0; ni < 4; ++ni) {
            const int n = n0 + wn + ni * 16 + ocol;
            const float bv = bias[n];
#pragma unroll
            for (int r = 0; r < 4; ++r) {
                const int m = m0 + wm + mi * 16 + orow + r;
                float v = acc[mi][ni][r] + bv;
                if (mode == M_SILU)      v = siluf(v);
                else if (mode == M_ELU1) v = (v > 0.f) ? (v + 1.f) : expf(v);
                else if (mode == M_GELU) v = geluf(v);
                const size_t oi = (size_t)m * ldc + n;
                if (mode == M_RES)  v += res[oi];
                if (Cb) Cb[oi] = f2bf(v);
                else    Cf[oi] = v;
            }
        }
    }
}

// ---------------- kmean: column mean of k (bf16, M x 384), two-stage ----------------
__global__ __launch_bounds__(384) void kmean_part_k(const u16* __restrict__ kbuf, float* __restrict__ part, int nb) {
    const int b = blockIdx.x, chunk = blockIdx.y;   // nb x 9
    const int c = threadIdx.x;
    const u16* p = kbuf + ((size_t)(b * L_TOK + chunk * 256)) * DIM + c;
    float s = 0.f;
    for (int n = 0; n < 256; ++n) s += bf2f(p[(size_t)n * DIM]);
    part[(size_t)(chunk * nb + b) * DIM + c] = s;
}

__global__ __launch_bounds__(384) void kmean_fin_k(const float* __restrict__ part, float* __restrict__ km, int nb) {
    const int b = blockIdx.x, c = threadIdx.x;
    float s = 0.f;
#pragma unroll
    for (int ch = 0; ch < 9; ++ch) s += part[(size_t)(ch * nb + b) * DIM + c];
    km[b * DIM + c] = s * (1.0f / L_TOK);
}

// ---------------- kv[b,h,d,e] = (1/L) sum_n rope(k)[n,d] * v[n,e]  (k,v bf16) ----------------
__global__ __launch_bounds__(256) void kv_k(const u16* __restrict__ kbuf, const u16* __restrict__ xi,
                                            const float* __restrict__ cosT, const float* __restrict__ sinT,
                                            float* __restrict__ kv) {
    const int b = blockIdx.x / NHEADS, h = blockIdx.x % NHEADS;
    __shared__ float ks[64][33];
    __shared__ float vs[64][33];
    const int tid = threadIdx.x;
    const int e0 = (tid & 15) * 2;
    const int d0 = (tid >> 4) * 2;
    float acc00 = 0.f, acc01 = 0.f, acc10 = 0.f, acc11 = 0.f;
    for (int n0 = 0; n0 < L_TOK; n0 += 64) {
#pragma unroll
        for (int j = 0; j < 4; ++j) {           // 1024 rope pairs
            int pi = tid + j * 256;
            int tn = pi >> 4;
            int pd = pi & 15;
            int n = n0 + tn;
            unsigned kk = *(const unsigned*)(kbuf + ((size_t)(b * L_TOK + n)) * DIM + h * 32 + pd * 2);
            float ka = bf2f((u16)(kk & 0xffffu)), kb2 = bf2f((u16)(kk >> 16));
            float cs = cosT[n * 192 + h * 16 + pd];
            float sn = sinT[n * 192 + h * 16 + pd];
            ks[tn][pd * 2]     = cs * ka - sn * kb2;
            ks[tn][pd * 2 + 1] = sn * ka + cs * kb2;
        }
#pragma unroll
        for (int j = 0; j < 4; ++j) {           // 2048 v elems as u16 pairs
            int pi = tid + j * 256;
            int tn = pi >> 4;
            int d = (pi & 15) * 2;
            unsigned vv = *(const unsigned*)(xi + ((size_t)(b * L_TOK + n0 + tn)) * DIM + h * 32 + d);
            vs[tn][d]     = bf2f((u16)(vv & 0xffffu));
            vs[tn][d + 1] = bf2f((u16)(vv >> 16));
        }
        __syncthreads();
#pragma unroll 8
        for (int n = 0; n < 64; ++n) {
            float k0v = ks[n][d0], k1v = ks[n][d0 + 1];
            float v0 = vs[n][e0], v1 = vs[n][e0 + 1];
            acc00 = fmaf(k0v, v0, acc00);
            acc01 = fmaf(k0v, v1, acc01);
            acc10 = fmaf(k1v, v0, acc10);
            acc11 = fmaf(k1v, v1, acc11);
        }
        __syncthreads();
    }
    const float inv = 1.0f / (float)L_TOK;
    float* o = kv + ((size_t)blockIdx.x * 32 + d0) * 32 + e0;
    o[0] = acc00 * inv; o[1] = acc01 * inv;
    o[32] = acc10 * inv; o[33] = acc11 * inv;
}

// ---------------- att (bf16 q in, bf16 att out) ----------------
__global__ __launch_bounds__(384) void att_k(const u16* __restrict__ q, const float* __restrict__ kv,
                                             const float* __restrict__ km,
                                             const float* __restrict__ cosT, const float* __restrict__ sinT,
                                             u16* __restrict__ out) {
    __shared__ float kvs[NHEADS * 32 * 32];   // 48 KB
    __shared__ float kms[DIM];
    __shared__ float sq[DIM];
    __shared__ float sqr[DIM];
    const int b = blockIdx.x / 48;
    const int chunk = blockIdx.x % 48;
    const int tid = threadIdx.x;
    for (int i = tid; i < NHEADS * 1024; i += 384) kvs[i] = kv[(size_t)b * (NHEADS * 1024) + i];
    kms[tid] = km[b * DIM + tid];
    __syncthreads();
    const int h = tid >> 5, e = tid & 31;
    const int p = tid >> 1;
    const float* kvh = &kvs[h * 1024];
    for (int ni = 0; ni < 48; ++ni) {
        const int n = chunk * 48 + ni;
        const float qv = bf2f(q[((size_t)(b * L_TOK + n)) * DIM + tid]);
        sq[tid] = qv;
        __syncthreads();
        float a = sq[tid & ~1], bb = sq[tid | 1];
        float cs = cosT[n * 192 + p], sn = sinT[n * 192 + p];
        sqr[tid] = (tid & 1) ? fmaf(sn, a, cs * bb) : fmaf(cs, a, -sn * bb);
        float zp = qv * kms[tid];
#pragma unroll
        for (int o = 16; o > 0; o >>= 1) zp += __shfl_xor(zp, o, 32);
        const float z = 1.0f / (zp + 1e-6f);
        __syncthreads();
        float dot = 0.f;
        const float* qrh = &sqr[h * 32];
#pragma unroll 8
        for (int d = 0; d < 32; ++d) dot = fmaf(qrh[d], kvh[d * 32 + e], dot);
        out[((size_t)(b * L_TOK + n)) * DIM + tid] = f2bf(z * dot);
        __syncthreads();
    }
}

extern "C" void kernel_launch(void* const* d_in, const int* in_sizes, int n_in,
                              void* d_out, int out_size, void* d_ws, size_t ws_size,
                              hipStream_t stream) {
    const float* x       = (const float*)d_in[0];
    const float* cpe1_w  = (const float*)d_in[3];
    const float* cpe1_b  = (const float*)d_in[4];
    const float* norm1_w = (const float*)d_in[5];
    const float* norm1_b = (const float*)d_in[6];
    const float* in_w    = (const float*)d_in[7];
    const float* in_b    = (const float*)d_in[8];
    const float* act_w   = (const float*)d_in[9];
    const float* act_b   = (const float*)d_in[10];
    const float* dwc_w   = (const float*)d_in[11];
    const float* dwc_b   = (const float*)d_in[12];
    const float* qk_w    = (const float*)d_in[13];
    const float* qk_b    = (const float*)d_in[14];
    const float* lepe_w  = (const float*)d_in[15];
    const float* lepe_b  = (const float*)d_in[16];
    const float* outp_w  = (const float*)d_in[17];
    const float* outp_b  = (const float*)d_in[18];
    const float* cpe2_w  = (const float*)d_in[19];
    const float* cpe2_b  = (const float*)d_in[20];
    const float* norm2_w = (const float*)d_in[21];
    const float* norm2_b = (const float*)d_in[22];
    const float* fc1_w   = (const float*)d_in[23];
    const float* fc1_b   = (const float*)d_in[24];
    const float* fc2_w   = (const float*)d_in[25];
    const float* fc2_b   = (const float*)d_in[26];
    float* out = (float*)d_out;

    float* ws = (float*)d_ws;
    const size_t TAB = (size_t)L_TOK * 192;
    const size_t NW_IN = 147456, NW_QK = 294912, NW_FC = 589824;
    const size_t WBF_U16 = NW_IN * 3 + NW_QK + NW_FC * 2;
    const size_t SMALL = 2 * TAB + (size_t)BATCH * DIM + 9 * (size_t)BATCH * DIM
                       + (size_t)BATCH * NHEADS * 1024 + WBF_U16 / 2;
    float* cosT = ws;
    float* sinT = cosT + TAB;
    float* km   = sinT + TAB;
    float* part = km + (size_t)BATCH * DIM;
    float* kvb  = part + 9 * (size_t)BATCH * DIM;
    u16*   wb_in  = (u16*)(kvb + (size_t)BATCH * NHEADS * 1024);
    u16*   wb_act = wb_in + NW_IN;
    u16*   wb_qk  = wb_act + NW_IN;
    u16*   wb_out = wb_qk + NW_QK;
    u16*   wb_fc1 = wb_out + NW_IN;
    u16*   wb_fc2 = wb_fc1 + NW_FC;
    float* gbuf = ws + SMALL;

    // 4 f32 group-units (W0..W3) + 0.5 unit bf16 xi (Wb); h spans W2+W3 as bf16
    const size_t avail = (ws_size / 4 > SMALL) ? (ws_size / 4 - SMALL) : 0;
    int nb = 0;
    for (int cand = BATCH; cand >= 1; cand >>= 1)
        if (9 * (size_t)cand * UNITB / 2 <= avail) { nb = cand; break; }
    if (nb == 0) {
        sentinel_k<<<1, 1, 0, stream>>>(out, (float)(ws_size >> 20));
        return;
    }

    cvtw_k<<<(int)(NW_IN / 1024), 256, 0, stream>>>(in_w, wb_in);
    cvtw_k<<<(int)(NW_IN / 1024), 256, 0, stream>>>(act_w, wb_act);
    cvtw_k<<<(int)(NW_QK / 1024), 256, 0, stream>>>(qk_w, wb_qk);
    cvtw_k<<<(int)(NW_IN / 1024), 256, 0, stream>>>(outp_w, wb_out);
    cvtw_k<<<(int)(NW_FC / 1024), 256, 0, stream>>>(fc1_w, wb_fc1);
    cvtw_k<<<(int)(NW_FC / 1024), 256, 0, stream>>>(fc2_w, wb_fc2);
    rope_tab_k<<<(int)((TAB + 255) / 256), 256, 0, stream>>>(cosT, sinT);

    for (int b0 = 0; b0 < BATCH; b0 += nb) {
        const size_t goff = (size_t)b0 * UNITB;
        const size_t GU   = (size_t)nb * UNITB;
        float* W0 = gbuf;             // x1 / x3 (f32 residual chain)
        float* W1 = gbuf + GU;        // xn(bf16) / q(bf16) / ao(bf16) / xn2(bf16)
        float* W2 = gbuf + 2 * GU;    // xi0(bf16) / act_res(bf16) / x2(f32) / h(bf16, W2+W3)
        u16*   Wb = (u16*)(gbuf + 4 * GU);   // xi (bf16)
        float* O  = out + goff;       // k(bf16) / att(bf16) / final out (f32)
        const float* Xg = x + goff;

        const dim3 DWG(18, nb * 4);
        const dim3 G384(3, nb * 18), G1536(12, nb * 18);

        // x1 = x + dwconv(x, cpe1) -> W0 f32
        dwconvf_k<<<DWG, 256, 0, stream>>>(Xg, cpe1_w, cpe1_b, W0);
        // xn = LN(x1) -> W1 bf16
        ln_k<<<nb * 576, 256, 0, stream>>>(W0, norm1_w, norm1_b, (u16*)W1);
        // xi0 = xn @ in_proj^T + b -> W2 bf16
        gemm_bf16<<<G384, 256, 0, stream>>>((u16*)W1, DIM, wb_in, DIM, in_b, nullptr,
                                            nullptr, (u16*)W2, DIM, DIM, M_BIAS);
        // xi = silu(dwconv(xi0, dwc)) -> Wb bf16
        dwconvb_k<<<DWG, 256, 0, stream>>>((u16*)W2, dwc_w, dwc_b, nullptr, nullptr, Wb, 1);
        // act_res = silu(xn @ act_proj^T + b) -> W2 bf16
        gemm_bf16<<<G384, 256, 0, stream>>>((u16*)W1, DIM, wb_act, DIM, act_b, nullptr,
                                            nullptr, (u16*)W2, DIM, DIM, M_SILU);
        // q = elu(xi @ qk_w[:384]^T + b) + 1 -> W1 bf16
        gemm_bf16<<<G384, 256, 0, stream>>>(Wb, DIM, wb_qk, DIM, qk_b, nullptr,
                                            nullptr, (u16*)W1, DIM, DIM, M_ELU1);
        // k = elu(xi @ qk_w[384:]^T + b) + 1 -> O bf16
        gemm_bf16<<<G384, 256, 0, stream>>>(Wb, DIM, wb_qk + (size_t)DIM * DIM, DIM, qk_b + DIM,
                                            nullptr, nullptr, (u16*)O, DIM, DIM, M_ELU1);
        // kmean over k (bf16)
        kmean_part_k<<<dim3(nb, 9), 384, 0, stream>>>((u16*)O, part, nb);
        kmean_fin_k<<<nb, 384, 0, stream>>>(part, km, nb);
        // kv from rope(k), v=xi (both bf16)
        kv_k<<<nb * NHEADS, 256, 0, stream>>>((u16*)O, Wb, cosT, sinT, kvb);
        // att -> O bf16 (overwrites k)
        att_k<<<nb * 48, 384, 0, stream>>>((u16*)W1, kvb, km, cosT, sinT, (u16*)O);
        // ao = (att + dwconv(xi, lepe)) * act_res -> W1 bf16
        dwconvb_k<<<DWG, 256, 0, stream>>>(Wb, lepe_w, lepe_b, (const u16*)O, (const u16*)W2,
                                           (u16*)W1, 3);
        // x2 = x1 + ao @ out_proj^T + b -> W2 f32
        gemm_bf16<<<G384, 256, 0, stream>>>((u16*)W1, DIM, wb_out, DIM, outp_b, W0,
                                            W2, nullptr, DIM, DIM, M_RES);
        // x3 = x2 + dwconv(x2, cpe2) -> W0 f32
        dwconvf_k<<<DWG, 256, 0, stream>>>(W2, cpe2_w, cpe2_b, W0);
        // xn2 = LN(x3) -> W1 bf16
        ln_k<<<nb * 576, 256, 0, stream>>>(W0, norm2_w, norm2_b, (u16*)W1);
        // h = gelu(xn2 @ fc1^T + b) -> W2+W3 bf16
        gemm_bf16<<<G1536, 256, 0, stream>>>((u16*)W1, DIM, wb_fc1, DIM, fc1_b, nullptr,
                                             nullptr, (u16*)W2, 1536, DIM, M_GELU);
        // O = x3 + h @ fc2^T + b2  (final, f32)
        gemm_bf16<<<G384, 256, 0, stream>>>((u16*)W2, 1536, wb_fc2, 1536, fc2_b, W0,
                                            O, nullptr, DIM, 1536, M_RES);
    }
}